// Round 4
// baseline (501.725 us; speedup 1.0000x reference)
//
#include <hip/hip_runtime.h>
#include <float.h>
#include <math.h>

#define NB 2
#define MQ 16384
#define NQ (NB*MQ)          // 32768 queries
#define PP 5023
#define KNN 4
#define HPX 256
#define HWSZ (HPX*HPX)      // 65536

// output layout (floats): densities[NQ], rgb[NQ*32], dist[NQ*4]
#define OUT_RGB_OFF  ((size_t)NQ)
#define OUT_DIST_OFF ((size_t)NQ + (size_t)NQ*32)

// workspace layout (bytes)
#define WS_SUMS_OFF ((size_t)NQ*KNN*4)   // after idx region (NQ*4 ints)
#define WS_TEX_OFF  ((size_t)1<<20)

// ------------------------------------------------------------------
// texture transpose: [n3][32][HW] -> [n3][HW][32]
__global__ __launch_bounds__(256) void k_transpose(const float* __restrict__ src,
                                                   float* __restrict__ dst) {
    const int tid = threadIdx.x;
    const int b = blockIdx.x;            // 6*256 blocks
    const int n3 = b >> 8;
    const int hw = ((b & 255) << 8) + tid;
    const float* s = src + (size_t)n3 * 32 * HWSZ + hw;
    float v[32];
#pragma unroll
    for (int c = 0; c < 32; ++c) v[c] = s[(size_t)c * HWSZ];
    float4* d = (float4*)(dst + ((size_t)n3 * HWSZ + hw) * 32);
#pragma unroll
    for (int c = 0; c < 8; ++c) d[c] = make_float4(v[4*c], v[4*c+1], v[4*c+2], v[4*c+3]);
}

// ------------------------------------------------------------------
// KNN v3: wave = 64 queries, points broadcast wave-uniform (scalar loads),
// packed u32 keys (d2-bits | idx), min/max sorted insert, 4-wave P-split.
__global__ __launch_bounds__(256) void k_knn(const float* __restrict__ coords,
                                             const float* __restrict__ pts,
                                             float* __restrict__ odist,
                                             int* __restrict__ oidx) {
    __shared__ unsigned int KB[4][4][64];   // [wave][slot][query]
    const int tid  = threadIdx.x;
    const int lane = tid & 63;
    const int w    = __builtin_amdgcn_readfirstlane(tid >> 6);  // 0..3
    const int q0   = blockIdx.x * 64;       // 512 blocks
    const int q    = q0 + lane;
    const int n    = q >> 14;
    const float cx = coords[q*3+0], cy = coords[q*3+1], cz = coords[q*3+2];
    const float cc = fmaf(cx, cx, fmaf(cy, cy, cz*cz));
    const float* __restrict__ pb = pts + (size_t)n * PP * 3;

    const int chunk  = (PP + 3) / 4;        // 1256
    const int pstart = w * chunk;
    const int pend   = (pstart + chunk < PP) ? (pstart + chunk) : PP;

    unsigned int k0 = 0xFFFFFFFFu, k1 = 0xFFFFFFFFu, k2 = 0xFFFFFFFFu, k3 = 0xFFFFFFFFu;

#pragma unroll 4
    for (int p = pstart; p < pend; ++p) {
        const float px = pb[3*p+0], py = pb[3*p+1], pz = pb[3*p+2]; // wave-uniform
        const float rx = cx - px, ry = cy - py, rz = cz - pz;
        const float dd = fmaf(rx, rx, fmaf(ry, ry, rz*rz));         // >= 0
        const unsigned int kb = (__float_as_uint(dd) & 0xFFFFE000u) | (unsigned int)p;
        unsigned int x;
        x  = (k0 > kb) ? k0 : kb;  k0 = (k0 < kb) ? k0 : kb;
        { unsigned int t = (k1 > x) ? k1 : x; k1 = (k1 < x) ? k1 : x; x = t; }
        { unsigned int t = (k2 > x) ? k2 : x; k2 = (k2 < x) ? k2 : x; x = t; }
        k3 = (k3 < x) ? k3 : x;
    }

    KB[w][0][lane] = k0; KB[w][1][lane] = k1; KB[w][2][lane] = k2; KB[w][3][lane] = k3;
    __syncthreads();

    if (w == 0) {
        unsigned int s0 = 0xFFFFFFFFu, s1 = 0xFFFFFFFFu, s2 = 0xFFFFFFFFu, s3 = 0xFFFFFFFFu;
#pragma unroll
        for (int ww = 0; ww < 4; ++ww)
#pragma unroll
            for (int j = 0; j < 4; ++j) {
                const unsigned int kb = KB[ww][j][lane];
                unsigned int x;
                x  = (s0 > kb) ? s0 : kb;  s0 = (s0 < kb) ? s0 : kb;
                { unsigned int t = (s1 > x) ? s1 : x; s1 = (s1 < x) ? s1 : x; x = t; }
                { unsigned int t = (s2 > x) ? s2 : x; s2 = (s2 < x) ? s2 : x; x = t; }
                s3 = (s3 < x) ? s3 : x;
            }
        // unpack, recompute exact d2 (reference formula), final sort-4
        int   id[4] = { (int)(s0 & 0x1FFFu), (int)(s1 & 0x1FFFu),
                        (int)(s2 & 0x1FFFu), (int)(s3 & 0x1FFFu) };
        float dv[4];
#pragma unroll
        for (int j = 0; j < 4; ++j) {
            const float px = pb[3*id[j]+0], py = pb[3*id[j]+1], pz = pb[3*id[j]+2];
            const float dt  = fmaf(cx, px, fmaf(cy, py, cz*pz));
            const float pp2 = fmaf(px, px, fmaf(py, py, pz*pz));
            dv[j] = fmaf(-2.0f, dt, cc + pp2);
        }
#define CSW(a,b) { bool sw = (dv[b] < dv[a]) || (dv[b] == dv[a] && id[b] < id[a]); \
                   if (sw) { float td=dv[a]; dv[a]=dv[b]; dv[b]=td; int ti=id[a]; id[a]=id[b]; id[b]=ti; } }
        CSW(0,1) CSW(2,3) CSW(0,2) CSW(1,3) CSW(1,2)
#undef CSW
        *(float4*)(odist + (size_t)q*4) = make_float4(dv[0], dv[1], dv[2], dv[3]);
        *(int4*)(oidx + (size_t)q*4)    = make_int4(id[0], id[1], id[2], id[3]);
    }
}

// ------------------------------------------------------------------
// per-(n,k) sum over m of 1/dist (deterministic)
__global__ __launch_bounds__(1024) void k_sums(const float* __restrict__ dist,
                                               float* __restrict__ sums) {
    const int b = blockIdx.x;            // n*4+k, 8 blocks
    const int n = b >> 2, k = b & 3;
    float s = 0.f;
    for (int m = threadIdx.x; m < MQ; m += 1024)
        s += 1.0f / dist[((size_t)n * MQ + m) * 4 + k];
    __shared__ float red[1024];
    red[threadIdx.x] = s;
    __syncthreads();
    for (int off = 512; off > 0; off >>= 1) {
        if (threadIdx.x < off) red[threadIdx.x] += red[threadIdx.x + off];
        __syncthreads();
    }
    if (threadIdx.x == 0) sums[b] = red[0];
}

// ------------------------------------------------------------------
// streaming gemv: activations read from LDS (column = lane), weights via
// wave-uniform s_load. NO per-lane x[] register array -> no scratch spill.
template<int DIN, int DOUT, int TILE>
__device__ __forceinline__ void gemv_lds(const float* __restrict__ X,  // LDS, [DIN][64]
                                         int lane,
                                         const float* __restrict__ W,
                                         const float* __restrict__ bias,
                                         int j0, float (&acc)[TILE]) {
#pragma unroll
    for (int u = 0; u < TILE; ++u) acc[u] = bias[j0 + u];
#pragma unroll
    for (int i = 0; i < DIN; ++i) {
        const float xv = X[i * 64 + lane];
        const float* wr = W + i * DOUT + j0;
#pragma unroll
        for (int u = 0; u < TILE; ++u) acc[u] = fmaf(xv, wr[u], acc[u]);
    }
}

// ------------------------------------------------------------------
// main fused kernel v4: single 32 KB LDS buffer, read-all->barrier->write
// in-place layers; 4 blocks/CU target (launch_bounds(512,8) caps VGPR at 64)
__global__ __launch_bounds__(512, 8) void k_main(
    const float* __restrict__ coords, const float* __restrict__ dirs,
    const float* __restrict__ pts, const float* __restrict__ tex_raw,
    const float* __restrict__ tex_t, const float* __restrict__ emb,
    const float* __restrict__ pw1, const float* __restrict__ pb1,
    const float* __restrict__ pw2, const float* __restrict__ pb2,
    const float* __restrict__ fw1, const float* __restrict__ fb1,
    const float* __restrict__ fw2, const float* __restrict__ fb2,
    const float* __restrict__ fw3, const float* __restrict__ fb3,
    const float* __restrict__ dw,  const float* __restrict__ db,
    const float* __restrict__ rw1, const float* __restrict__ rb1,
    const float* __restrict__ rw2, const float* __restrict__ rb2,
    const int* __restrict__ idxbuf, const float* __restrict__ distbuf,
    const float* __restrict__ sums, float* __restrict__ out, int use_tex_t)
{
    __shared__ float S[128 * 64];        // 32 KB, rows 0..127 x 64 queries
    const int tid  = threadIdx.x;
    const int lane = tid & 63;
    const int wv   = __builtin_amdgcn_readfirstlane(tid >> 6);   // 0..7
    const int q0   = blockIdx.x * 64;
    const int n    = q0 >> 14;

    // ---------- phase 1: triplane sampling -> registers (4 ch/wave) ----------
    float tex_acc[4];
    {
        const int m = lane, g = wv;
        const int q = q0 + m;
        const float cx = coords[q*3+0], cy = coords[q*3+1], cz = coords[q*3+2];
#pragma unroll
        for (int u = 0; u < 4; ++u) tex_acc[u] = 0.f;
#pragma unroll
        for (int pl = 0; pl < 3; ++pl) {
            float gx = (pl == 2) ? cz : cx;
            float gy = (pl == 0) ? cy : ((pl == 1) ? cz : cx);
            float x = (gx + 1.f) * 128.f - 0.5f;
            float y = (gy + 1.f) * 128.f - 0.5f;
            float x0f = floorf(x), y0f = floorf(y);
            float wx1 = x - x0f, wy1 = y - y0f;
            float wx0 = 1.f - wx1, wy0 = 1.f - wy1;
            int x0 = (int)x0f, y0 = (int)y0f;
            int n3 = n * 3 + pl;
            int  xs[4] = { x0, x0+1, x0,   x0+1 };
            int  ys[4] = { y0, y0,   y0+1, y0+1 };
            float wt[4] = { wx0*wy0, wx1*wy0, wx0*wy1, wx1*wy1 };
#pragma unroll
            for (int c = 0; c < 4; ++c) {
                int xi = xs[c], yi = ys[c];
                if (xi >= 0 && xi < HPX && yi >= 0 && yi < HPX) {
                    float wgt = wt[c];
                    if (use_tex_t) {
                        const float4 a = *(const float4*)(tex_t +
                            (((size_t)n3 * HWSZ + (size_t)yi * HPX + xi) * 32 + g * 4));
                        tex_acc[0] = fmaf(wgt, a.x, tex_acc[0]);
                        tex_acc[1] = fmaf(wgt, a.y, tex_acc[1]);
                        tex_acc[2] = fmaf(wgt, a.z, tex_acc[2]);
                        tex_acc[3] = fmaf(wgt, a.w, tex_acc[3]);
                    } else {
                        size_t base = ((size_t)(n3 * 32 + g * 4)) * HWSZ + (size_t)yi * HPX + xi;
#pragma unroll
                        for (int u = 0; u < 4; ++u)
                            tex_acc[u] = fmaf(wgt, tex_raw[base + (size_t)u * HWSZ], tex_acc[u]);
                    }
                }
            }
        }
#pragma unroll
        for (int u = 0; u < 4; ++u) tex_acc[u] *= (1.f / 3.f);
    }

    // ---------- phase 2: per-neighbor point MLP (rows 64..122 = x59,
    //            rows 0..63 = h1), k sequential ----------
    float pts_acc[4];
#pragma unroll
    for (int u = 0; u < 4; ++u) pts_acc[u] = 0.f;

#pragma unroll 1
    for (int k = 0; k < KNN; ++k) {
        // k.a: build x59 into rows 64..122
        {
            const int m = lane, g = wv;
            const int q = q0 + m;
            const int id = idxbuf[(size_t)q*4 + k];
            const float4 ea = *(const float4*)(emb + (size_t)id * 32 + g * 4);
            S[(64 + g*4 + 0)*64 + m] = ea.x; S[(64 + g*4 + 1)*64 + m] = ea.y;
            S[(64 + g*4 + 2)*64 + m] = ea.z; S[(64 + g*4 + 3)*64 + m] = ea.w;

            const float cx = coords[q*3+0], cy = coords[q*3+1], cz = coords[q*3+2];
            const float nx = pts[((size_t)n*PP + id)*3 + 0];
            const float ny = pts[((size_t)n*PP + id)*3 + 1];
            const float nz = pts[((size_t)n*PP + id)*3 + 2];
            float rx = cx - nx, ry = cy - ny, rz = cz - nz;
            float nrm = sqrtf(fmaf(rx, rx, fmaf(ry, ry, rz*rz)));
            float inv = 1.f / fmaxf(nrm, 1e-12f);
            rx *= inv; ry *= inv; rz *= inv;
            const int h0 = g * 4;
#pragma unroll
            for (int hh = 0; hh < 4; ++hh) {
                int h = h0 + hh;
                if (h < 27) {
                    float v;
                    if (h < 24) {
                        int base = (h < 12) ? h : (h - 12);
                        float rv = (base >> 2) == 0 ? rx : ((base >> 2) == 1 ? ry : rz);
                        float e = rv * (float)(1 << (base & 3));
                        v = (h < 12) ? sinf(e) : cosf(e);
                    } else {
                        v = (h == 24) ? rx : ((h == 25) ? ry : rz);
                    }
                    S[(96 + h)*64 + m] = v;
                }
            }
        }
        __syncthreads();
        // k.b: p1 59->64 relu (reads rows 64..122, writes rows 0..63 disjoint)
        {
            float acc[8];
            gemv_lds<59, 64, 8>(S + 64*64, lane, pw1, pb1, wv * 8, acc);
#pragma unroll
            for (int u = 0; u < 8; ++u) S[(wv*8 + u)*64 + lane] = fmaxf(acc[u], 0.f);
        }
        __syncthreads();
        // k.c: p2 64->32 (reads rows 0..63), accumulate w_k * h2
        {
            float acc[4];
            gemv_lds<64, 32, 4>(S, lane, pw2, pb2, wv * 4, acc);
            const int q = q0 + lane;
            float dist = distbuf[(size_t)q*4 + k];
            float wk = (1.0f / dist) / sums[n*4 + k];
#pragma unroll
            for (int u = 0; u < 4; ++u) pts_acc[u] = fmaf(wk, acc[u], pts_acc[u]);
        }
        // no barrier needed: next k.a writes rows 64..122 (disjoint from reads
        // of rows 0..63 here); the barrier after next k.a orders k.b's writes.
    }
    __syncthreads();
    // feat = [tex(rows 0..31); pts(rows 32..63)]
#pragma unroll
    for (int u = 0; u < 4; ++u) {
        S[(wv*4 + u)*64 + lane]      = tex_acc[u];
        S[(32 + wv*4 + u)*64 + lane] = pts_acc[u];
    }
    __syncthreads();

    // ---------- dense stack (in-place: read-all -> barrier -> write) ----------
    // fw1: 64 -> 128 relu
    {
        float acc[16];
        gemv_lds<64, 128, 16>(S, lane, fw1, fb1, wv * 16, acc);
        __syncthreads();
#pragma unroll
        for (int u = 0; u < 16; ++u) S[(wv*16 + u)*64 + lane] = fmaxf(acc[u], 0.f);
    }
    __syncthreads();
    // fw2: 128 -> 128 relu
    {
        float acc[16];
        gemv_lds<128, 128, 16>(S, lane, fw2, fb2, wv * 16, acc);
        __syncthreads();
#pragma unroll
        for (int u = 0; u < 16; ++u) S[(wv*16 + u)*64 + lane] = fmaxf(acc[u], 0.f);
    }
    __syncthreads();
    // fw3: 128 -> 128 (no relu)
    {
        float acc[16];
        gemv_lds<128, 128, 16>(S, lane, fw3, fb3, wv * 16, acc);
        __syncthreads();
#pragma unroll
        for (int u = 0; u < 16; ++u) S[(wv*16 + u)*64 + lane] = acc[u];
    }
    __syncthreads();
    // head: density + rw1 155->64 relu (feat in rows 0..127)
    {
        const int q = q0 + lane;
        if (wv == 0) {
            float z = db[0];
#pragma unroll
            for (int i = 0; i < 128; ++i) z = fmaf(S[i*64 + lane], dw[i], z);
            const float cx = coords[q*3+0], cy = coords[q*3+1], cz = coords[q*3+2];
            float selv = (cx > -1.f && cx < 1.f && cy > -1.f && cy < 1.f &&
                          cz > -1.f && cz < 1.f) ? 1.f : 0.f;
            float t10 = 10.f * z;
            float sp = (t10 > 20.f) ? t10 : log1pf(expf(t10));
            float raw = sp * 0.1f * selv;
            out[q] = 1.f - expf(-raw);
        }
        float dx = dirs[q*3+0], dy = dirs[q*3+1], dz = dirs[q*3+2];
        float dn = sqrtf(fmaf(dx, dx, fmaf(dy, dy, dz*dz)));
        float inv = 1.f / fmaxf(dn, 1e-12f);
        dx *= inv; dy *= inv; dz *= inv;
        float hv[27];
#pragma unroll
        for (int c3 = 0; c3 < 3; ++c3) {
            float rv = (c3 == 0) ? dx : ((c3 == 1) ? dy : dz);
            float f = 1.f;
#pragma unroll
            for (int fr = 0; fr < 4; ++fr) {
                float e = rv * f;
                hv[c3*4 + fr] = sinf(e);
                hv[12 + c3*4 + fr] = cosf(e);
                f *= 2.f;
            }
        }
        hv[24] = dx; hv[25] = dy; hv[26] = dz;
        const int j0 = wv * 8;
        float acc[8];
        gemv_lds<128, 64, 8>(S, lane, rw1, rb1, j0, acc);   // first 128 dims
#pragma unroll
        for (int h = 0; h < 27; ++h) {                      // remaining 27 dims
            const float* wr = rw1 + (128 + h) * 64 + j0;
#pragma unroll
            for (int u = 0; u < 8; ++u) acc[u] = fmaf(hv[h], wr[u], acc[u]);
        }
        __syncthreads();
#pragma unroll
        for (int u = 0; u < 8; ++u) S[(j0 + u)*64 + lane] = fmaxf(acc[u], 0.f);
    }
    __syncthreads();
    // rw2: 64 -> 32, sigmoid on first 3
    {
        float acc[4];
        gemv_lds<64, 32, 4>(S, lane, rw2, rb2, wv * 4, acc);
        const int q = q0 + lane;
#pragma unroll
        for (int u = 0; u < 4; ++u) {
            int j = wv*4 + u;
            float v = acc[u];
            if (j < 3) v = 1.002f * (1.f / (1.f + expf(-v))) - 0.001f;
            out[OUT_RGB_OFF + (size_t)q*32 + j] = v;
        }
    }
}

// ------------------------------------------------------------------
extern "C" void kernel_launch(void* const* d_in, const int* in_sizes, int n_in,
                              void* d_out, int out_size, void* d_ws, size_t ws_size,
                              hipStream_t stream) {
    (void)in_sizes; (void)n_in; (void)out_size;
    const float* coords = (const float*)d_in[0];
    const float* dirs   = (const float*)d_in[1];
    const float* pts    = (const float*)d_in[2];
    const float* tex    = (const float*)d_in[3];
    const float* emb    = (const float*)d_in[4];
    const float* pw1 = (const float*)d_in[5];  const float* pb1 = (const float*)d_in[6];
    const float* pw2 = (const float*)d_in[7];  const float* pb2 = (const float*)d_in[8];
    const float* fw1 = (const float*)d_in[9];  const float* fb1 = (const float*)d_in[10];
    const float* fw2 = (const float*)d_in[11]; const float* fb2 = (const float*)d_in[12];
    const float* fw3 = (const float*)d_in[13]; const float* fb3 = (const float*)d_in[14];
    const float* dw  = (const float*)d_in[15]; const float* db  = (const float*)d_in[16];
    const float* rw1 = (const float*)d_in[17]; const float* rb1 = (const float*)d_in[18];
    const float* rw2 = (const float*)d_in[19]; const float* rb2 = (const float*)d_in[20];

    float* out    = (float*)d_out;
    int*   wsidx  = (int*)d_ws;
    float* wssums = (float*)((char*)d_ws + WS_SUMS_OFF);
    float* wstex  = (float*)((char*)d_ws + WS_TEX_OFF);

    const size_t need_tex = WS_TEX_OFF + (size_t)6 * HWSZ * 32 * 4;
    const int use_t = (ws_size >= need_tex) ? 1 : 0;

    if (use_t) k_transpose<<<6 * 256, 256, 0, stream>>>(tex, wstex);
    k_knn<<<NQ / 64, 256, 0, stream>>>(coords, pts, out + OUT_DIST_OFF, wsidx);
    k_sums<<<8, 1024, 0, stream>>>(out + OUT_DIST_OFF, wssums);
    k_main<<<NQ / 64, 512, 0, stream>>>(coords, dirs, pts, tex, wstex, emb,
                                        pw1, pb1, pw2, pb2,
                                        fw1, fb1, fw2, fb2, fw3, fb3,
                                        dw, db, rw1, rb1, rw2, rb2,
                                        wsidx, out + OUT_DIST_OFF, wssums, out, use_t);
}

// Round 5
// 426.430 us; speedup vs baseline: 1.1766x; 1.1766x over previous
//
#include <hip/hip_runtime.h>
#include <float.h>
#include <math.h>

#define NB 2
#define MQ 16384
#define NQ (NB*MQ)          // 32768 queries
#define PP 5023
#define KNN 4
#define HPX 256
#define HWSZ (HPX*HPX)      // 65536

// output layout (floats): densities[NQ], rgb[NQ*32], dist[NQ*4]
#define OUT_RGB_OFF  ((size_t)NQ)
#define OUT_DIST_OFF ((size_t)NQ + (size_t)NQ*32)

// workspace layout (bytes)
#define WS_SUMS_OFF ((size_t)NQ*KNN*4)   // after idx region (NQ*4 ints)
#define WS_TEX_OFF  ((size_t)1<<20)

// ------------------------------------------------------------------
// texture transpose: [n3][32][HW] -> [n3][HW][32]
__global__ __launch_bounds__(256) void k_transpose(const float* __restrict__ src,
                                                   float* __restrict__ dst) {
    const int tid = threadIdx.x;
    const int b = blockIdx.x;            // 6*256 blocks
    const int n3 = b >> 8;
    const int hw = ((b & 255) << 8) + tid;
    const float* s = src + (size_t)n3 * 32 * HWSZ + hw;
    float v[32];
#pragma unroll
    for (int c = 0; c < 32; ++c) v[c] = s[(size_t)c * HWSZ];
    float4* d = (float4*)(dst + ((size_t)n3 * HWSZ + hw) * 32);
#pragma unroll
    for (int c = 0; c < 8; ++c) d[c] = make_float4(v[4*c], v[4*c+1], v[4*c+2], v[4*c+3]);
}

// ------------------------------------------------------------------
// KNN v4: 16 waves/block, wave = all 64 queries of the block, P split 16 ways.
// n is SCALAR (q0>>14) so point loads are wave-uniform s_loads (broadcast).
// Packed u32 keys (upper d2 bits | idx), 7-op min/max sorted insert.
__global__ __launch_bounds__(1024, 2) void k_knn(const float* __restrict__ coords,
                                                 const float* __restrict__ pts,
                                                 float* __restrict__ odist,
                                                 int* __restrict__ oidx) {
    __shared__ unsigned int KB[16][4][64];   // [wave][slot][query] = 16 KB
    const int tid  = threadIdx.x;
    const int lane = tid & 63;
    const int w    = __builtin_amdgcn_readfirstlane(tid >> 6);  // 0..15
    const int q0   = blockIdx.x * 64;       // 512 blocks
    const int q    = q0 + lane;
    const int n    = q0 >> 14;              // SCALAR: block's queries share n
    const float cx = coords[q*3+0], cy = coords[q*3+1], cz = coords[q*3+2];
    const float* __restrict__ pb = pts + (size_t)n * PP * 3;   // scalar base

    const int chunk  = (PP + 15) / 16;      // 314
    const int pstart = w * chunk;
    const int pend   = (pstart + chunk < PP) ? (pstart + chunk) : PP;

    unsigned int k0 = 0xFFFFFFFFu, k1 = 0xFFFFFFFFu, k2 = 0xFFFFFFFFu, k3 = 0xFFFFFFFFu;

#pragma unroll 4
    for (int p = pstart; p < pend; ++p) {
        const float px = pb[3*p+0], py = pb[3*p+1], pz = pb[3*p+2]; // s_load broadcast
        const float rx = cx - px, ry = cy - py, rz = cz - pz;
        const float dd = fmaf(rx, rx, fmaf(ry, ry, rz*rz));         // >= 0
        const unsigned int kb = (__float_as_uint(dd) & 0xFFFFE000u) | (unsigned int)p;
        // sorted insert, 7 ops (med3-fusable): uses old values top-down
        unsigned int m2 = (kb > k2) ? kb : k2;  k3 = (k3 < m2) ? k3 : m2;
        unsigned int m1 = (kb > k1) ? kb : k1;  k2 = (k2 < m1) ? k2 : m1;
        unsigned int m0 = (kb > k0) ? kb : k0;  k1 = (k1 < m0) ? k1 : m0;
        k0 = (k0 < kb) ? k0 : kb;
    }

    KB[w][0][lane] = k0; KB[w][1][lane] = k1; KB[w][2][lane] = k2; KB[w][3][lane] = k3;
    __syncthreads();

    if (w == 0) {
        unsigned int s0 = 0xFFFFFFFFu, s1 = 0xFFFFFFFFu, s2 = 0xFFFFFFFFu, s3 = 0xFFFFFFFFu;
#pragma unroll
        for (int ww = 0; ww < 16; ++ww)
#pragma unroll
            for (int j = 0; j < 4; ++j) {
                const unsigned int kb = KB[ww][j][lane];
                unsigned int m2 = (kb > s2) ? kb : s2;  s3 = (s3 < m2) ? s3 : m2;
                unsigned int m1 = (kb > s1) ? kb : s1;  s2 = (s2 < m1) ? s2 : m1;
                unsigned int m0 = (kb > s0) ? kb : s0;  s1 = (s1 < m0) ? s1 : m0;
                s0 = (s0 < kb) ? s0 : kb;
            }
        // unpack, recompute exact d2 (reference formula), final sort-4
        const float cc = fmaf(cx, cx, fmaf(cy, cy, cz*cz));
        int   id[4] = { (int)(s0 & 0x1FFFu), (int)(s1 & 0x1FFFu),
                        (int)(s2 & 0x1FFFu), (int)(s3 & 0x1FFFu) };
        float dv[4];
#pragma unroll
        for (int j = 0; j < 4; ++j) {
            const float px = pb[3*id[j]+0], py = pb[3*id[j]+1], pz = pb[3*id[j]+2];
            const float dt  = fmaf(cx, px, fmaf(cy, py, cz*pz));
            const float pp2 = fmaf(px, px, fmaf(py, py, pz*pz));
            dv[j] = fmaf(-2.0f, dt, cc + pp2);
        }
#define CSW(a,b) { bool sw = (dv[b] < dv[a]) || (dv[b] == dv[a] && id[b] < id[a]); \
                   if (sw) { float td=dv[a]; dv[a]=dv[b]; dv[b]=td; int ti=id[a]; id[a]=id[b]; id[b]=ti; } }
        CSW(0,1) CSW(2,3) CSW(0,2) CSW(1,3) CSW(1,2)
#undef CSW
        *(float4*)(odist + (size_t)q*4) = make_float4(dv[0], dv[1], dv[2], dv[3]);
        *(int4*)(oidx + (size_t)q*4)    = make_int4(id[0], id[1], id[2], id[3]);
    }
}

// ------------------------------------------------------------------
// per-(n,k) sum over m of 1/dist (deterministic)
__global__ __launch_bounds__(1024) void k_sums(const float* __restrict__ dist,
                                               float* __restrict__ sums) {
    const int b = blockIdx.x;            // n*4+k, 8 blocks
    const int n = b >> 2, k = b & 3;
    float s = 0.f;
    for (int m = threadIdx.x; m < MQ; m += 1024)
        s += 1.0f / dist[((size_t)n * MQ + m) * 4 + k];
    __shared__ float red[1024];
    red[threadIdx.x] = s;
    __syncthreads();
    for (int off = 512; off > 0; off >>= 1) {
        if (threadIdx.x < off) red[threadIdx.x] += red[threadIdx.x + off];
        __syncthreads();
    }
    if (threadIdx.x == 0) sums[b] = red[0];
}

// ------------------------------------------------------------------
// streaming gemv: activations read from LDS (column = lane), weights via
// wave-uniform s_load. NO per-lane x[] register array -> no scratch spill.
template<int DIN, int DOUT, int TILE>
__device__ __forceinline__ void gemv_lds(const float* __restrict__ X,  // LDS, [DIN][64]
                                         int lane,
                                         const float* __restrict__ W,
                                         const float* __restrict__ bias,
                                         int j0, float (&acc)[TILE]) {
#pragma unroll
    for (int u = 0; u < TILE; ++u) acc[u] = bias[j0 + u];
#pragma unroll
    for (int i = 0; i < DIN; ++i) {
        const float xv = X[i * 64 + lane];
        const float* wr = W + i * DOUT + j0;
#pragma unroll
        for (int u = 0; u < TILE; ++u) acc[u] = fmaf(xv, wr[u], acc[u]);
    }
}

// ------------------------------------------------------------------
// main fused kernel v5: 16 waves / 64 queries per block, tile-8 j-split,
// ping-pong A/B (64 KB), grid 512 -> 2 blocks/CU = 32 waves/CU (100%).
// launch_bounds(1024,2): VGPR cap 64 (empirical: cap = 2048/(arg*waves/blk)).
__global__ __launch_bounds__(1024, 2) void k_main(
    const float* __restrict__ coords, const float* __restrict__ dirs,
    const float* __restrict__ pts, const float* __restrict__ tex_raw,
    const float* __restrict__ tex_t, const float* __restrict__ emb,
    const float* __restrict__ pw1, const float* __restrict__ pb1,
    const float* __restrict__ pw2, const float* __restrict__ pb2,
    const float* __restrict__ fw1, const float* __restrict__ fb1,
    const float* __restrict__ fw2, const float* __restrict__ fb2,
    const float* __restrict__ fw3, const float* __restrict__ fb3,
    const float* __restrict__ dw,  const float* __restrict__ db,
    const float* __restrict__ rw1, const float* __restrict__ rb1,
    const float* __restrict__ rw2, const float* __restrict__ rb2,
    const int* __restrict__ idxbuf, const float* __restrict__ distbuf,
    const float* __restrict__ sums, float* __restrict__ out, int use_tex_t)
{
    __shared__ float A[128 * 64];
    __shared__ float B[128 * 64];
    const int tid  = threadIdx.x;
    const int lane = tid & 63;
    const int wv   = __builtin_amdgcn_readfirstlane(tid >> 6);   // 0..15
    const int q0   = blockIdx.x * 64;
    const int n    = q0 >> 14;

    // ---------- phase 1: triplane sampling -> registers (2 ch/wave) ----------
    float tex_acc[2];
    {
        const int m = lane, g = wv;
        const int q = q0 + m;
        const float cx = coords[q*3+0], cy = coords[q*3+1], cz = coords[q*3+2];
        tex_acc[0] = 0.f; tex_acc[1] = 0.f;
#pragma unroll
        for (int pl = 0; pl < 3; ++pl) {
            float gx = (pl == 2) ? cz : cx;
            float gy = (pl == 0) ? cy : ((pl == 1) ? cz : cx);
            float x = (gx + 1.f) * 128.f - 0.5f;
            float y = (gy + 1.f) * 128.f - 0.5f;
            float x0f = floorf(x), y0f = floorf(y);
            float wx1 = x - x0f, wy1 = y - y0f;
            float wx0 = 1.f - wx1, wy0 = 1.f - wy1;
            int x0 = (int)x0f, y0 = (int)y0f;
            int n3 = n * 3 + pl;
            int  xs[4] = { x0, x0+1, x0,   x0+1 };
            int  ys[4] = { y0, y0,   y0+1, y0+1 };
            float wt[4] = { wx0*wy0, wx1*wy0, wx0*wy1, wx1*wy1 };
#pragma unroll
            for (int c = 0; c < 4; ++c) {
                int xi = xs[c], yi = ys[c];
                if (xi >= 0 && xi < HPX && yi >= 0 && yi < HPX) {
                    float wgt = wt[c];
                    if (use_tex_t) {
                        const float2 a = *(const float2*)(tex_t +
                            (((size_t)n3 * HWSZ + (size_t)yi * HPX + xi) * 32 + g * 2));
                        tex_acc[0] = fmaf(wgt, a.x, tex_acc[0]);
                        tex_acc[1] = fmaf(wgt, a.y, tex_acc[1]);
                    } else {
                        size_t base = ((size_t)(n3 * 32 + g * 2)) * HWSZ + (size_t)yi * HPX + xi;
                        tex_acc[0] = fmaf(wgt, tex_raw[base], tex_acc[0]);
                        tex_acc[1] = fmaf(wgt, tex_raw[base + HWSZ], tex_acc[1]);
                    }
                }
            }
        }
        tex_acc[0] *= (1.f / 3.f); tex_acc[1] *= (1.f / 3.f);
    }

    // ---------- phase 2: per-neighbor point MLP ----------
    // B rows 64..122 = x59, B rows 0..63 = h1 (ping within B)
    float pts_acc[2];
    pts_acc[0] = 0.f; pts_acc[1] = 0.f;

#pragma unroll 1
    for (int k = 0; k < KNN; ++k) {
        // k.a: build x59 into B rows 64..122
        {
            const int m = lane, g = wv;
            const int q = q0 + m;
            const int id = idxbuf[(size_t)q*4 + k];
            const float2 ea = *(const float2*)(emb + (size_t)id * 32 + g * 2);
            B[(64 + g*2 + 0)*64 + m] = ea.x;
            B[(64 + g*2 + 1)*64 + m] = ea.y;

            const float cx = coords[q*3+0], cy = coords[q*3+1], cz = coords[q*3+2];
            const float nx = pts[((size_t)n*PP + id)*3 + 0];
            const float ny = pts[((size_t)n*PP + id)*3 + 1];
            const float nz = pts[((size_t)n*PP + id)*3 + 2];
            float rx = cx - nx, ry = cy - ny, rz = cz - nz;
            float nrm = sqrtf(fmaf(rx, rx, fmaf(ry, ry, rz*rz)));
            float inv = 1.f / fmaxf(nrm, 1e-12f);
            rx *= inv; ry *= inv; rz *= inv;
            // harmonic rows 96..122: wave g handles h in {2g, 2g+1} ∩ [0,27)
#pragma unroll
            for (int hh = 0; hh < 2; ++hh) {
                int h = g*2 + hh;
                if (h < 27) {
                    float v;
                    if (h < 24) {
                        int base = (h < 12) ? h : (h - 12);
                        float rv = (base >> 2) == 0 ? rx : ((base >> 2) == 1 ? ry : rz);
                        float e = rv * (float)(1 << (base & 3));
                        v = (h < 12) ? sinf(e) : cosf(e);
                    } else {
                        v = (h == 24) ? rx : ((h == 25) ? ry : rz);
                    }
                    B[(96 + h)*64 + m] = v;
                }
            }
        }
        __syncthreads();
        // k.b: p1 59->64 relu (reads rows 64..122, writes rows 0..63 disjoint)
        {
            float acc[4];
            gemv_lds<59, 64, 4>(B + 64*64, lane, pw1, pb1, wv * 4, acc);
#pragma unroll
            for (int u = 0; u < 4; ++u) B[(wv*4 + u)*64 + lane] = fmaxf(acc[u], 0.f);
        }
        __syncthreads();
        // k.c: p2 64->32 (reads rows 0..63), accumulate w_k * h2
        {
            float acc[2];
            gemv_lds<64, 32, 2>(B, lane, pw2, pb2, wv * 2, acc);
            const int q = q0 + lane;
            float dist = distbuf[(size_t)q*4 + k];
            float wk = (1.0f / dist) / sums[n*4 + k];
            pts_acc[0] = fmaf(wk, acc[0], pts_acc[0]);
            pts_acc[1] = fmaf(wk, acc[1], pts_acc[1]);
        }
        // no barrier: next k.a writes rows 64..122, disjoint from k.c reads;
        // k.b reads of rows 64..122 completed before the post-k.b barrier.
    }
    __syncthreads();
    // feat -> A: rows 0..31 tex, rows 32..63 pts
    {
        A[(wv*2 + 0)*64 + lane]      = tex_acc[0];
        A[(wv*2 + 1)*64 + lane]      = tex_acc[1];
        A[(32 + wv*2 + 0)*64 + lane] = pts_acc[0];
        A[(32 + wv*2 + 1)*64 + lane] = pts_acc[1];
    }
    __syncthreads();

    // ---------- dense stack (ping-pong A/B, no inner barriers) ----------
    // fw1: 64 -> 128 relu, A -> B
    {
        float acc[8];
        gemv_lds<64, 128, 8>(A, lane, fw1, fb1, wv * 8, acc);
#pragma unroll
        for (int u = 0; u < 8; ++u) B[(wv*8 + u)*64 + lane] = fmaxf(acc[u], 0.f);
    }
    __syncthreads();
    // fw2: 128 -> 128 relu, B -> A
    {
        float acc[8];
        gemv_lds<128, 128, 8>(B, lane, fw2, fb2, wv * 8, acc);
#pragma unroll
        for (int u = 0; u < 8; ++u) A[(wv*8 + u)*64 + lane] = fmaxf(acc[u], 0.f);
    }
    __syncthreads();
    // fw3: 128 -> 128 (no relu), A -> B
    {
        float acc[8];
        gemv_lds<128, 128, 8>(A, lane, fw3, fb3, wv * 8, acc);
#pragma unroll
        for (int u = 0; u < 8; ++u) B[(wv*8 + u)*64 + lane] = acc[u];
    }
    __syncthreads();
    // ray harmonic -> A rows 64..90 (2 values/wave; kills hv[27] reg array)
    {
        const int q = q0 + lane;
        float dx = dirs[q*3+0], dy = dirs[q*3+1], dz = dirs[q*3+2];
        float dn = sqrtf(fmaf(dx, dx, fmaf(dy, dy, dz*dz)));
        float inv = 1.f / fmaxf(dn, 1e-12f);
        dx *= inv; dy *= inv; dz *= inv;
#pragma unroll
        for (int hh = 0; hh < 2; ++hh) {
            int h = wv*2 + hh;
            if (h < 27) {
                float v;
                if (h < 24) {
                    int base = (h < 12) ? h : (h - 12);
                    float rv = (base >> 2) == 0 ? dx : ((base >> 2) == 1 ? dy : dz);
                    float e = rv * (float)(1 << (base & 3));
                    v = (h < 12) ? sinf(e) : cosf(e);
                } else {
                    v = (h == 24) ? dx : ((h == 25) ? dy : dz);
                }
                A[(64 + h)*64 + lane] = v;
            }
        }
    }
    __syncthreads();
    // head: density (wave 0) + rw1 155->64 relu (feat B rows 0..127 + A rows 64..90)
    {
        const int q = q0 + lane;
        if (wv == 0) {
            float z = db[0];
#pragma unroll
            for (int i = 0; i < 128; ++i) z = fmaf(B[i*64 + lane], dw[i], z);
            const float cx = coords[q*3+0], cy = coords[q*3+1], cz = coords[q*3+2];
            float selv = (cx > -1.f && cx < 1.f && cy > -1.f && cy < 1.f &&
                          cz > -1.f && cz < 1.f) ? 1.f : 0.f;
            float t10 = 10.f * z;
            float sp = (t10 > 20.f) ? t10 : log1pf(expf(t10));
            float raw = sp * 0.1f * selv;
            out[q] = 1.f - expf(-raw);
        }
        const int j0 = wv * 4;
        float acc[4];
        gemv_lds<128, 64, 4>(B, lane, rw1, rb1, j0, acc);   // first 128 dims
#pragma unroll
        for (int h = 0; h < 27; ++h) {                      // dims 128..154 from A
            const float xv = A[(64 + h)*64 + lane];
            const float* wr = rw1 + (128 + h) * 64 + j0;
#pragma unroll
            for (int u = 0; u < 4; ++u) acc[u] = fmaf(xv, wr[u], acc[u]);
        }
        // writes rows 0..63 of A, disjoint from reads of rows 64..90
#pragma unroll
        for (int u = 0; u < 4; ++u) A[(j0 + u)*64 + lane] = fmaxf(acc[u], 0.f);
    }
    __syncthreads();
    // rw2: 64 -> 32, sigmoid on first 3
    {
        float acc[2];
        gemv_lds<64, 32, 2>(A, lane, rw2, rb2, wv * 2, acc);
        const int q = q0 + lane;
#pragma unroll
        for (int u = 0; u < 2; ++u) {
            int j = wv*2 + u;
            float v = acc[u];
            if (j < 3) v = 1.002f * (1.f / (1.f + expf(-v))) - 0.001f;
            out[OUT_RGB_OFF + (size_t)q*32 + j] = v;
        }
    }
}

// ------------------------------------------------------------------
extern "C" void kernel_launch(void* const* d_in, const int* in_sizes, int n_in,
                              void* d_out, int out_size, void* d_ws, size_t ws_size,
                              hipStream_t stream) {
    (void)in_sizes; (void)n_in; (void)out_size;
    const float* coords = (const float*)d_in[0];
    const float* dirs   = (const float*)d_in[1];
    const float* pts    = (const float*)d_in[2];
    const float* tex    = (const float*)d_in[3];
    const float* emb    = (const float*)d_in[4];
    const float* pw1 = (const float*)d_in[5];  const float* pb1 = (const float*)d_in[6];
    const float* pw2 = (const float*)d_in[7];  const float* pb2 = (const float*)d_in[8];
    const float* fw1 = (const float*)d_in[9];  const float* fb1 = (const float*)d_in[10];
    const float* fw2 = (const float*)d_in[11]; const float* fb2 = (const float*)d_in[12];
    const float* fw3 = (const float*)d_in[13]; const float* fb3 = (const float*)d_in[14];
    const float* dw  = (const float*)d_in[15]; const float* db  = (const float*)d_in[16];
    const float* rw1 = (const float*)d_in[17]; const float* rb1 = (const float*)d_in[18];
    const float* rw2 = (const float*)d_in[19]; const float* rb2 = (const float*)d_in[20];

    float* out    = (float*)d_out;
    int*   wsidx  = (int*)d_ws;
    float* wssums = (float*)((char*)d_ws + WS_SUMS_OFF);
    float* wstex  = (float*)((char*)d_ws + WS_TEX_OFF);

    const size_t need_tex = WS_TEX_OFF + (size_t)6 * HWSZ * 32 * 4;
    const int use_t = (ws_size >= need_tex) ? 1 : 0;

    if (use_t) k_transpose<<<6 * 256, 256, 0, stream>>>(tex, wstex);
    k_knn<<<NQ / 64, 1024, 0, stream>>>(coords, pts, out + OUT_DIST_OFF, wsidx);
    k_sums<<<8, 1024, 0, stream>>>(out + OUT_DIST_OFF, wssums);
    k_main<<<NQ / 64, 1024, 0, stream>>>(coords, dirs, pts, tex, wstex, emb,
                                         pw1, pb1, pw2, pb2,
                                         fw1, fb1, fw2, fb2, fw3, fb3,
                                         dw, db, rw1, rb1, rw2, rb2,
                                         wsidx, out + OUT_DIST_OFF, wssums, out, use_t);
}

// Round 6
// 359.908 us; speedup vs baseline: 1.3940x; 1.1848x over previous
//
#include <hip/hip_runtime.h>
#include <float.h>
#include <math.h>

#define NB 2
#define MQ 16384
#define NQ (NB*MQ)          // 32768 queries
#define PP 5023
#define KNN 4
#define HPX 256
#define HWSZ (HPX*HPX)      // 65536

// output layout (floats): densities[NQ], rgb[NQ*32], dist[NQ*4]
#define OUT_RGB_OFF  ((size_t)NQ)
#define OUT_DIST_OFF ((size_t)NQ + (size_t)NQ*32)

// workspace layout (bytes)
#define WS_SUMS_OFF ((size_t)NQ*KNN*4)       // 512 KB: 8 floats
#define WS_PTS4_OFF ((size_t)0x90000)        // 576 KB: 2*5023*16 B
#define WS_WP_OFF   ((size_t)0xC0000)        // 768 KB: 29504 u32 = 118 KB
#define WS_TEX_OFF  ((size_t)1<<20)          // 1 MB: 48 MB transposed tex

// packed-weight sub-offsets (u32 units)
#define WP_PW1 0
#define WP_PW2 1920
#define WP_FW1 2944
#define WP_FW2 7040
#define WP_FW3 15232
#define WP_DW  23424
#define WP_RW1 23488
#define WP_RW2 28480
#define WP_TOTAL 29504

typedef __attribute__((ext_vector_type(2))) _Float16 half2v;

static __device__ __forceinline__ unsigned int pk2(float a, float b) {
    half2v h; h[0] = (_Float16)a; h[1] = (_Float16)b;   // RNE converts
    return __builtin_bit_cast(unsigned int, h);
}
static __device__ __forceinline__ float dot2(unsigned int a, unsigned int b, float c) {
    return __builtin_amdgcn_fdot2(__builtin_bit_cast(half2v, a),
                                  __builtin_bit_cast(half2v, b), c, false);
}

// ------------------------------------------------------------------
// weight pack: fp32 [DIN][DOUT] -> f16x2 [(DIN+1)/2][DOUT] (pairs across DIN)
struct PackArgs {
    const float* src[8];
    int off[8]; int din[8]; int dout[8];
};
__global__ __launch_bounds__(256) void k_pack(PackArgs a, unsigned int* wp) {
    const int mid = blockIdx.y;
    const int idx = blockIdx.x * 256 + threadIdx.x;
    const int DIN = a.din[mid], DOUT = a.dout[mid];
    const int din2 = (DIN + 1) >> 1;
    if (idx >= din2 * DOUT) return;
    const int i2 = idx / DOUT, j = idx - i2 * DOUT;
    const float* s = a.src[mid];
    const float lo = s[(2*i2) * DOUT + j];
    const float hi = (2*i2 + 1 < DIN) ? s[(2*i2 + 1) * DOUT + j] : 0.f;
    wp[a.off[mid] + idx] = pk2(lo, hi);
}

// pts4 = (x, y, z, |p|^2)
__global__ __launch_bounds__(256) void k_pts4(const float* __restrict__ pts,
                                              float4* __restrict__ o) {
    const int i = blockIdx.x * 256 + threadIdx.x;
    if (i >= NB * PP) return;
    const float px = pts[3*i], py = pts[3*i+1], pz = pts[3*i+2];
    o[i] = make_float4(px, py, pz, fmaf(px, px, fmaf(py, py, pz*pz)));
}

// ------------------------------------------------------------------
// texture transpose: [n3][32][HW] -> [n3][HW][32]
__global__ __launch_bounds__(256) void k_transpose(const float* __restrict__ src,
                                                   float* __restrict__ dst) {
    const int tid = threadIdx.x;
    const int b = blockIdx.x;            // 6*256 blocks
    const int n3 = b >> 8;
    const int hw = ((b & 255) << 8) + tid;
    const float* s = src + (size_t)n3 * 32 * HWSZ + hw;
    float v[32];
#pragma unroll
    for (int c = 0; c < 32; ++c) v[c] = s[(size_t)c * HWSZ];
    float4* d = (float4*)(dst + ((size_t)n3 * HWSZ + hw) * 32);
#pragma unroll
    for (int c = 0; c < 8; ++c) d[c] = make_float4(v[4*c], v[4*c+1], v[4*c+2], v[4*c+3]);
}

// ------------------------------------------------------------------
// KNN v5: 16 waves/block, wave = the block's 64 queries, P split 16 ways.
// pts4 gives one s_load_dwordx4/point; dot-form d2; __any-guarded insert.
__global__ __launch_bounds__(1024, 2) void k_knn(const float* __restrict__ coords,
                                                 const float4* __restrict__ pts4,
                                                 const float* __restrict__ pts,
                                                 float* __restrict__ odist,
                                                 int* __restrict__ oidx) {
    __shared__ unsigned int KB[16][4][64];
    const int tid  = threadIdx.x;
    const int lane = tid & 63;
    const int w    = __builtin_amdgcn_readfirstlane(tid >> 6);  // 0..15
    const int q0   = blockIdx.x * 64;       // 512 blocks
    const int q    = q0 + lane;
    const int n    = q0 >> 14;              // scalar
    const float cx = coords[q*3+0], cy = coords[q*3+1], cz = coords[q*3+2];
    const float cc = fmaf(cx, cx, fmaf(cy, cy, cz*cz));
    const float4* __restrict__ p4 = pts4 + (size_t)n * PP;     // scalar base

    const int chunk  = (PP + 15) / 16;      // 314
    const int pstart = w * chunk;
    const int pend   = (pstart + chunk < PP) ? (pstart + chunk) : PP;

    unsigned int k0 = 0xFFFFFFFFu, k1 = 0xFFFFFFFFu, k2 = 0xFFFFFFFFu, k3 = 0xFFFFFFFFu;

#pragma unroll 2
    for (int p = pstart; p < pend; ++p) {
        const float4 P = p4[p];                                 // s_load_dwordx4
        const float dot = fmaf(cx, P.x, fmaf(cy, P.y, cz * P.z));
        float dd = fmaf(-2.0f, dot, cc + P.w);
        dd = fmaxf(dd, 0.f);                                    // guard cancellation
        const unsigned int kb = (__float_as_uint(dd) & 0xFFFFE000u) | (unsigned int)p;
        if (__any(kb < k3)) {
            unsigned int m2 = (kb > k2) ? kb : k2;  k3 = (k3 < m2) ? k3 : m2;
            unsigned int m1 = (kb > k1) ? kb : k1;  k2 = (k2 < m1) ? k2 : m1;
            unsigned int m0 = (kb > k0) ? kb : k0;  k1 = (k1 < m0) ? k1 : m0;
            k0 = (k0 < kb) ? k0 : kb;
        }
    }

    KB[w][0][lane] = k0; KB[w][1][lane] = k1; KB[w][2][lane] = k2; KB[w][3][lane] = k3;
    __syncthreads();

    if (w == 0) {
        unsigned int s0 = 0xFFFFFFFFu, s1 = 0xFFFFFFFFu, s2 = 0xFFFFFFFFu, s3 = 0xFFFFFFFFu;
#pragma unroll
        for (int ww = 0; ww < 16; ++ww)
#pragma unroll
            for (int j = 0; j < 4; ++j) {
                const unsigned int kb = KB[ww][j][lane];
                unsigned int m2 = (kb > s2) ? kb : s2;  s3 = (s3 < m2) ? s3 : m2;
                unsigned int m1 = (kb > s1) ? kb : s1;  s2 = (s2 < m1) ? s2 : m1;
                unsigned int m0 = (kb > s0) ? kb : s0;  s1 = (s1 < m0) ? s1 : m0;
                s0 = (s0 < kb) ? s0 : kb;
            }
        const float* __restrict__ pb = pts + (size_t)n * PP * 3;
        int   id[4] = { (int)(s0 & 0x1FFFu), (int)(s1 & 0x1FFFu),
                        (int)(s2 & 0x1FFFu), (int)(s3 & 0x1FFFu) };
        float dv[4];
#pragma unroll
        for (int j = 0; j < 4; ++j) {
            const float px = pb[3*id[j]+0], py = pb[3*id[j]+1], pz = pb[3*id[j]+2];
            const float dt  = fmaf(cx, px, fmaf(cy, py, cz*pz));
            const float pp2 = fmaf(px, px, fmaf(py, py, pz*pz));
            dv[j] = fmaf(-2.0f, dt, cc + pp2);
        }
#define CSW(a,b) { bool sw = (dv[b] < dv[a]) || (dv[b] == dv[a] && id[b] < id[a]); \
                   if (sw) { float td=dv[a]; dv[a]=dv[b]; dv[b]=td; int ti=id[a]; id[a]=id[b]; id[b]=ti; } }
        CSW(0,1) CSW(2,3) CSW(0,2) CSW(1,3) CSW(1,2)
#undef CSW
        *(float4*)(odist + (size_t)q*4) = make_float4(dv[0], dv[1], dv[2], dv[3]);
        *(int4*)(oidx + (size_t)q*4)    = make_int4(id[0], id[1], id[2], id[3]);
    }
}

// ------------------------------------------------------------------
// per-(n,k) sum over m of 1/dist (deterministic)
__global__ __launch_bounds__(1024) void k_sums(const float* __restrict__ dist,
                                               float* __restrict__ sums) {
    const int b = blockIdx.x;            // n*4+k, 8 blocks
    const int n = b >> 2, k = b & 3;
    float s = 0.f;
    for (int m = threadIdx.x; m < MQ; m += 1024)
        s += 1.0f / dist[((size_t)n * MQ + m) * 4 + k];
    __shared__ float red[1024];
    red[threadIdx.x] = s;
    __syncthreads();
    for (int off = 512; off > 0; off >>= 1) {
        if (threadIdx.x < off) red[threadIdx.x] += red[threadIdx.x + off];
        __syncthreads();
    }
    if (threadIdx.x == 0) sums[b] = red[0];
}

// ------------------------------------------------------------------
// packed gemv: activations f16x2 from LDS (col = lane), weights f16x2 via
// wave-uniform s_load; fp32 accumulate via v_dot2_f32_f16.
template<int DIN2, int DOUT, int TILE>
__device__ __forceinline__ void gemv_p(const unsigned int* __restrict__ Xp, int lane,
                                       const unsigned int* __restrict__ Wp,
                                       const float* __restrict__ bias,
                                       int j0, float (&acc)[TILE]) {
#pragma unroll
    for (int u = 0; u < TILE; ++u) acc[u] = bias[j0 + u];
#pragma unroll
    for (int i2 = 0; i2 < DIN2; ++i2) {
        const unsigned int xv = Xp[i2 * 64 + lane];
        const unsigned int* wr = Wp + i2 * DOUT + j0;
#pragma unroll
        for (int u = 0; u < TILE; ++u) acc[u] = dot2(xv, wr[u], acc[u]);
    }
}

// harmonic value h of [sin(e) x12, cos(e) x12, r x3], e = r * 2^(h&3)
static __device__ __forceinline__ float harm_val(int h, float rx, float ry, float rz) {
    if (h >= 27) return 0.f;
    float v;
    if (h < 24) {
        int base = (h < 12) ? h : (h - 12);
        float rv = (base >> 2) == 0 ? rx : ((base >> 2) == 1 ? ry : rz);
        float e = rv * (float)(1 << (base & 3));
        v = (h < 12) ? sinf(e) : cosf(e);
    } else {
        v = (h == 24) ? rx : ((h == 25) ? ry : rz);
    }
    return v;
}

// ------------------------------------------------------------------
// main fused kernel v6: f16x2 packed activations/weights, v_dot2 gemv.
// 16 waves / 64 queries per block; Ap/Bp 16 KB each -> 32 KB LDS/block.
__global__ __launch_bounds__(1024, 2) void k_main(
    const float* __restrict__ coords, const float* __restrict__ dirs,
    const float* __restrict__ pts, const float* __restrict__ tex_raw,
    const float* __restrict__ tex_t, const float* __restrict__ emb,
    const unsigned int* __restrict__ wp,
    const float* __restrict__ pb1, const float* __restrict__ pb2,
    const float* __restrict__ fb1, const float* __restrict__ fb2,
    const float* __restrict__ fb3, const float* __restrict__ db,
    const float* __restrict__ rb1, const float* __restrict__ rb2,
    const int* __restrict__ idxbuf, const float* __restrict__ distbuf,
    const float* __restrict__ sums, float* __restrict__ out, int use_tex_t)
{
    __shared__ unsigned int Ap[64 * 64];   // 16 KB
    __shared__ unsigned int Bp[64 * 64];   // 16 KB
    const int tid  = threadIdx.x;
    const int lane = tid & 63;
    const int wv   = __builtin_amdgcn_readfirstlane(tid >> 6);   // 0..15
    const int q0   = blockIdx.x * 64;
    const int n    = q0 >> 14;

    // ---------- phase 1: triplane sampling -> fp32 regs (2 ch/wave) ----------
    float tex_acc[2] = {0.f, 0.f};
    {
        const int m = lane, g = wv;
        const int q = q0 + m;
        const float cx = coords[q*3+0], cy = coords[q*3+1], cz = coords[q*3+2];
#pragma unroll
        for (int pl = 0; pl < 3; ++pl) {
            float gx = (pl == 2) ? cz : cx;
            float gy = (pl == 0) ? cy : ((pl == 1) ? cz : cx);
            float x = (gx + 1.f) * 128.f - 0.5f;
            float y = (gy + 1.f) * 128.f - 0.5f;
            float x0f = floorf(x), y0f = floorf(y);
            float wx1 = x - x0f, wy1 = y - y0f;
            float wx0 = 1.f - wx1, wy0 = 1.f - wy1;
            int x0 = (int)x0f, y0 = (int)y0f;
            int n3 = n * 3 + pl;
            int  xs[4] = { x0, x0+1, x0,   x0+1 };
            int  ys[4] = { y0, y0,   y0+1, y0+1 };
            float wt[4] = { wx0*wy0, wx1*wy0, wx0*wy1, wx1*wy1 };
#pragma unroll
            for (int c = 0; c < 4; ++c) {
                int xi = xs[c], yi = ys[c];
                if (xi >= 0 && xi < HPX && yi >= 0 && yi < HPX) {
                    float wgt = wt[c];
                    if (use_tex_t) {
                        const float2 a = *(const float2*)(tex_t +
                            (((size_t)n3 * HWSZ + (size_t)yi * HPX + xi) * 32 + g * 2));
                        tex_acc[0] = fmaf(wgt, a.x, tex_acc[0]);
                        tex_acc[1] = fmaf(wgt, a.y, tex_acc[1]);
                    } else {
                        size_t base = ((size_t)(n3 * 32 + g * 2)) * HWSZ + (size_t)yi * HPX + xi;
                        tex_acc[0] = fmaf(wgt, tex_raw[base], tex_acc[0]);
                        tex_acc[1] = fmaf(wgt, tex_raw[base + HWSZ], tex_acc[1]);
                    }
                }
            }
        }
        tex_acc[0] *= (1.f / 3.f); tex_acc[1] *= (1.f / 3.f);
    }

    // ---------- phase 2: per-neighbor point MLP ----------
    // Bp rows 32..61 = x59 packed (emb rows 32..47, harm rows 48..61)
    // Bp rows  0..31 = h1 packed
    float pts_acc[2] = {0.f, 0.f};

#pragma unroll 1
    for (int k = 0; k < KNN; ++k) {
        {
            const int m = lane, g = wv;
            const int q = q0 + m;
            const int id = idxbuf[(size_t)q*4 + k];
            const float2 ea = *(const float2*)(emb + (size_t)id * 32 + g * 2);
            Bp[(32 + g)*64 + m] = pk2(ea.x, ea.y);

            const float cx = coords[q*3+0], cy = coords[q*3+1], cz = coords[q*3+2];
            const float nx = pts[((size_t)n*PP + id)*3 + 0];
            const float ny = pts[((size_t)n*PP + id)*3 + 1];
            const float nz = pts[((size_t)n*PP + id)*3 + 2];
            float rx = cx - nx, ry = cy - ny, rz = cz - nz;
            float nrm = sqrtf(fmaf(rx, rx, fmaf(ry, ry, rz*rz)));
            float inv = 1.f / fmaxf(nrm, 1e-12f);
            rx *= inv; ry *= inv; rz *= inv;
            if (g < 14) {
                float v0 = harm_val(2*g,     rx, ry, rz);
                float v1 = harm_val(2*g + 1, rx, ry, rz);
                Bp[(48 + g)*64 + m] = pk2(v0, v1);
            }
        }
        __syncthreads();
        // p1: 59(pad60) -> 64, relu; reads rows 32..61, writes rows 0..31
        {
            float acc[4];
            gemv_p<30, 64, 4>(Bp + 32*64, lane, wp + WP_PW1, pb1, wv * 4, acc);
            Bp[(2*wv    )*64 + lane] = pk2(fmaxf(acc[0], 0.f), fmaxf(acc[1], 0.f));
            Bp[(2*wv + 1)*64 + lane] = pk2(fmaxf(acc[2], 0.f), fmaxf(acc[3], 0.f));
        }
        __syncthreads();
        // p2: 64 -> 32 (reads rows 0..31), fp32 accumulate w_k * h2
        {
            float acc[2];
            gemv_p<32, 32, 2>(Bp, lane, wp + WP_PW2, pb2, wv * 2, acc);
            const int q = q0 + lane;
            float dist = distbuf[(size_t)q*4 + k];
            float wk = (1.0f / dist) / sums[n*4 + k];
            pts_acc[0] = fmaf(wk, acc[0], pts_acc[0]);
            pts_acc[1] = fmaf(wk, acc[1], pts_acc[1]);
        }
        // no barrier: next k.a writes rows 32..61 (disjoint from p2 reads);
        // post-k.a barrier orders p1's row 0..31 writes vs p2 reads.
    }
    __syncthreads();
    // feat -> Ap rows 0..31: tex pairs rows 0..15, pts pairs rows 16..31
    Ap[wv*64 + lane]        = pk2(tex_acc[0], tex_acc[1]);
    Ap[(16 + wv)*64 + lane] = pk2(pts_acc[0], pts_acc[1]);
    __syncthreads();

    // fw1: 64 -> 128 relu, Ap -> Bp rows 0..63
    {
        float acc[8];
        gemv_p<32, 128, 8>(Ap, lane, wp + WP_FW1, fb1, wv * 8, acc);
#pragma unroll
        for (int u = 0; u < 4; ++u)
            Bp[(4*wv + u)*64 + lane] = pk2(fmaxf(acc[2*u], 0.f), fmaxf(acc[2*u+1], 0.f));
    }
    __syncthreads();
    // fw2: 128 -> 128 relu, Bp -> Ap
    {
        float acc[8];
        gemv_p<64, 128, 8>(Bp, lane, wp + WP_FW2, fb2, wv * 8, acc);
#pragma unroll
        for (int u = 0; u < 4; ++u)
            Ap[(4*wv + u)*64 + lane] = pk2(fmaxf(acc[2*u], 0.f), fmaxf(acc[2*u+1], 0.f));
    }
    __syncthreads();
    // fw3: 128 -> 128 (no relu), Ap -> Bp
    {
        float acc[8];
        gemv_p<64, 128, 8>(Ap, lane, wp + WP_FW3, fb3, wv * 8, acc);
#pragma unroll
        for (int u = 0; u < 4; ++u)
            Bp[(4*wv + u)*64 + lane] = pk2(acc[2*u], acc[2*u+1]);
    }
    __syncthreads();
    // ray harmonics -> Ap rows 0..13 (waves 0..13); density on wave 15
    {
        const int q = q0 + lane;
        if (wv < 14) {
            float dx = dirs[q*3+0], dy = dirs[q*3+1], dz = dirs[q*3+2];
            float dn = sqrtf(fmaf(dx, dx, fmaf(dy, dy, dz*dz)));
            float inv = 1.f / fmaxf(dn, 1e-12f);
            dx *= inv; dy *= inv; dz *= inv;
            float v0 = harm_val(2*wv,     dx, dy, dz);
            float v1 = harm_val(2*wv + 1, dx, dy, dz);
            Ap[wv*64 + lane] = pk2(v0, v1);
        } else if (wv == 15) {
            float z = db[0];
            const unsigned int* dwp = wp + WP_DW;
#pragma unroll
            for (int i2 = 0; i2 < 64; ++i2) z = dot2(Bp[i2*64 + lane], dwp[i2], z);
            const float cx = coords[q*3+0], cy = coords[q*3+1], cz = coords[q*3+2];
            float selv = (cx > -1.f && cx < 1.f && cy > -1.f && cy < 1.f &&
                          cz > -1.f && cz < 1.f) ? 1.f : 0.f;
            float t10 = 10.f * z;
            float sp = (t10 > 20.f) ? t10 : log1pf(expf(t10));
            float raw = sp * 0.1f * selv;
            out[q] = 1.f - expf(-raw);
        }
    }
    __syncthreads();
    // rw1: 155(pad156) -> 64 relu; feat = Bp rows 0..63 (+wp rows 0..63),
    // harm = Ap rows 0..13 (+wp rows 64..77); writes Ap rows 16..47
    {
        const int j0 = wv * 4;
        float acc[4];
        gemv_p<64, 64, 4>(Bp, lane, wp + WP_RW1, rb1, j0, acc);
#pragma unroll
        for (int t = 0; t < 14; ++t) {
            const unsigned int xv = Ap[t*64 + lane];
            const unsigned int* wr = wp + WP_RW1 + (64 + t) * 64 + j0;
#pragma unroll
            for (int u = 0; u < 4; ++u) acc[u] = dot2(xv, wr[u], acc[u]);
        }
        Ap[(16 + 2*wv    )*64 + lane] = pk2(fmaxf(acc[0], 0.f), fmaxf(acc[1], 0.f));
        Ap[(16 + 2*wv + 1)*64 + lane] = pk2(fmaxf(acc[2], 0.f), fmaxf(acc[3], 0.f));
    }
    __syncthreads();
    // rw2: 64 -> 32, sigmoid on first 3; reads Ap rows 16..47
    {
        float acc[2];
        gemv_p<32, 32, 2>(Ap + 16*64, lane, wp + WP_RW2, rb2, wv * 2, acc);
        const int q = q0 + lane;
#pragma unroll
        for (int u = 0; u < 2; ++u) {
            int j = wv*2 + u;
            float v = acc[u];
            if (j < 3) v = 1.002f * (1.f / (1.f + expf(-v))) - 0.001f;
            out[OUT_RGB_OFF + (size_t)q*32 + j] = v;
        }
    }
}

// ------------------------------------------------------------------
extern "C" void kernel_launch(void* const* d_in, const int* in_sizes, int n_in,
                              void* d_out, int out_size, void* d_ws, size_t ws_size,
                              hipStream_t stream) {
    (void)in_sizes; (void)n_in; (void)out_size;
    const float* coords = (const float*)d_in[0];
    const float* dirs   = (const float*)d_in[1];
    const float* pts    = (const float*)d_in[2];
    const float* tex    = (const float*)d_in[3];
    const float* emb    = (const float*)d_in[4];
    const float* pw1 = (const float*)d_in[5];  const float* pb1 = (const float*)d_in[6];
    const float* pw2 = (const float*)d_in[7];  const float* pb2 = (const float*)d_in[8];
    const float* fw1 = (const float*)d_in[9];  const float* fb1 = (const float*)d_in[10];
    const float* fw2 = (const float*)d_in[11]; const float* fb2 = (const float*)d_in[12];
    const float* fw3 = (const float*)d_in[13]; const float* fb3 = (const float*)d_in[14];
    const float* dw  = (const float*)d_in[15]; const float* db  = (const float*)d_in[16];
    const float* rw1 = (const float*)d_in[17]; const float* rb1 = (const float*)d_in[18];
    const float* rw2 = (const float*)d_in[19]; const float* rb2 = (const float*)d_in[20];

    float*        out    = (float*)d_out;
    int*          wsidx  = (int*)d_ws;
    float*        wssums = (float*)((char*)d_ws + WS_SUMS_OFF);
    float4*       wspts4 = (float4*)((char*)d_ws + WS_PTS4_OFF);
    unsigned int* wswp   = (unsigned int*)((char*)d_ws + WS_WP_OFF);
    float*        wstex  = (float*)((char*)d_ws + WS_TEX_OFF);

    const size_t need_tex = WS_TEX_OFF + (size_t)6 * HWSZ * 32 * 4;
    const int use_t = (ws_size >= need_tex) ? 1 : 0;

    PackArgs pa;
    pa.src[0] = pw1; pa.off[0] = WP_PW1; pa.din[0] = 59;  pa.dout[0] = 64;
    pa.src[1] = pw2; pa.off[1] = WP_PW2; pa.din[1] = 64;  pa.dout[1] = 32;
    pa.src[2] = fw1; pa.off[2] = WP_FW1; pa.din[2] = 64;  pa.dout[2] = 128;
    pa.src[3] = fw2; pa.off[3] = WP_FW2; pa.din[3] = 128; pa.dout[3] = 128;
    pa.src[4] = fw3; pa.off[4] = WP_FW3; pa.din[4] = 128; pa.dout[4] = 128;
    pa.src[5] = dw;  pa.off[5] = WP_DW;  pa.din[5] = 128; pa.dout[5] = 1;
    pa.src[6] = rw1; pa.off[6] = WP_RW1; pa.din[6] = 155; pa.dout[6] = 64;
    pa.src[7] = rw2; pa.off[7] = WP_RW2; pa.din[7] = 64;  pa.dout[7] = 32;

    k_pack<<<dim3(32, 8), 256, 0, stream>>>(pa, wswp);
    k_pts4<<<(NB*PP + 255)/256, 256, 0, stream>>>(pts, wspts4);
    if (use_t) k_transpose<<<6 * 256, 256, 0, stream>>>(tex, wstex);
    k_knn<<<NQ / 64, 1024, 0, stream>>>(coords, wspts4, pts, out + OUT_DIST_OFF, wsidx);
    k_sums<<<8, 1024, 0, stream>>>(out + OUT_DIST_OFF, wssums);
    k_main<<<NQ / 64, 1024, 0, stream>>>(coords, dirs, pts, tex, wstex, emb,
                                         wswp, pb1, pb2, fb1, fb2, fb3, db, rb1, rb2,
                                         wsidx, out + OUT_DIST_OFF, wssums, out, use_t);
}

// Round 7
// 330.425 us; speedup vs baseline: 1.5184x; 1.0892x over previous
//
#include <hip/hip_runtime.h>
#include <float.h>
#include <math.h>

#define NB 2
#define MQ 16384
#define NQ (NB*MQ)          // 32768 queries
#define PP 5023
#define KNN 4
#define HPX 256
#define HWSZ (HPX*HPX)      // 65536

// output layout (floats): densities[NQ], rgb[NQ*32], dist[NQ*4]
#define OUT_RGB_OFF  ((size_t)NQ)
#define OUT_DIST_OFF ((size_t)NQ + (size_t)NQ*32)

// workspace layout (bytes)
#define WS_SUMS_OFF ((size_t)NQ*KNN*4)       // 512 KB: 8 floats
#define WS_PTS4_OFF ((size_t)0x90000)        // 576 KB: 2*5023*16 B
#define WS_WP_OFF   ((size_t)0xC0000)        // 768 KB: 29504 u32 = 118 KB
#define WS_TEX_OFF  ((size_t)1<<20)          // 1 MB: 48 MB transposed tex

// packed-weight sub-offsets (u32 units)
#define WP_PW1 0
#define WP_PW2 1920
#define WP_FW1 2944
#define WP_FW2 7040
#define WP_FW3 15232
#define WP_DW  23424
#define WP_RW1 23488
#define WP_RW2 28480

typedef __attribute__((ext_vector_type(2))) _Float16 half2v;

static __device__ __forceinline__ unsigned int pk2(float a, float b) {
    half2v h; h[0] = (_Float16)a; h[1] = (_Float16)b;   // RNE converts
    return __builtin_bit_cast(unsigned int, h);
}
static __device__ __forceinline__ float2 upk(unsigned int u) {
    half2v h = __builtin_bit_cast(half2v, u);
    return make_float2((float)h[0], (float)h[1]);
}
static __device__ __forceinline__ float dot2(unsigned int a, unsigned int b, float c) {
    return __builtin_amdgcn_fdot2(__builtin_bit_cast(half2v, a),
                                  __builtin_bit_cast(half2v, b), c, false);
}

// ------------------------------------------------------------------
// weight pack: fp32 [DIN][DOUT] -> f16x2 [(DIN+1)/2][DOUT] (pairs across DIN)
struct PackArgs {
    const float* src[8];
    int off[8]; int din[8]; int dout[8];
};
__global__ __launch_bounds__(256) void k_pack(PackArgs a, unsigned int* wp) {
    const int mid = blockIdx.y;
    const int idx = blockIdx.x * 256 + threadIdx.x;
    const int DIN = a.din[mid], DOUT = a.dout[mid];
    const int din2 = (DIN + 1) >> 1;
    if (idx >= din2 * DOUT) return;
    const int i2 = idx / DOUT, j = idx - i2 * DOUT;
    const float* s = a.src[mid];
    const float lo = s[(2*i2) * DOUT + j];
    const float hi = (2*i2 + 1 < DIN) ? s[(2*i2 + 1) * DOUT + j] : 0.f;
    wp[a.off[mid] + idx] = pk2(lo, hi);
}

// pts4 = (x, y, z, |p|^2)
__global__ __launch_bounds__(256) void k_pts4(const float* __restrict__ pts,
                                              float4* __restrict__ o) {
    const int i = blockIdx.x * 256 + threadIdx.x;
    if (i >= NB * PP) return;
    const float px = pts[3*i], py = pts[3*i+1], pz = pts[3*i+2];
    o[i] = make_float4(px, py, pz, fmaf(px, px, fmaf(py, py, pz*pz)));
}

// ------------------------------------------------------------------
// texture transpose: [n3][32][HW] -> [n3][HW][32]
__global__ __launch_bounds__(256) void k_transpose(const float* __restrict__ src,
                                                   float* __restrict__ dst) {
    const int tid = threadIdx.x;
    const int b = blockIdx.x;            // 6*256 blocks
    const int n3 = b >> 8;
    const int hw = ((b & 255) << 8) + tid;
    const float* s = src + (size_t)n3 * 32 * HWSZ + hw;
    float v[32];
#pragma unroll
    for (int c = 0; c < 32; ++c) v[c] = s[(size_t)c * HWSZ];
    float4* d = (float4*)(dst + ((size_t)n3 * HWSZ + hw) * 32);
#pragma unroll
    for (int c = 0; c < 8; ++c) d[c] = make_float4(v[4*c], v[4*c+1], v[4*c+2], v[4*c+3]);
}

// ------------------------------------------------------------------
// KNN v6: 16 waves/block, wave = the block's 64 queries, P split 16 ways.
// Unguarded 8-point batches: 8 s_load_dwordx4 issued back-to-back, then
// 8 insert bodies -> one lgkmcnt wait per 8 points instead of per point.
__global__ __launch_bounds__(1024, 2) void k_knn(const float* __restrict__ coords,
                                                 const float4* __restrict__ pts4,
                                                 const float* __restrict__ pts,
                                                 float* __restrict__ odist,
                                                 int* __restrict__ oidx) {
    __shared__ unsigned int KB[16][4][64];
    const int tid  = threadIdx.x;
    const int lane = tid & 63;
    const int w    = __builtin_amdgcn_readfirstlane(tid >> 6);  // 0..15
    const int q0   = blockIdx.x * 64;       // 512 blocks
    const int q    = q0 + lane;
    const int n    = q0 >> 14;              // scalar
    const float cx = coords[q*3+0], cy = coords[q*3+1], cz = coords[q*3+2];
    const float cc = fmaf(cx, cx, fmaf(cy, cy, cz*cz));
    const float4* __restrict__ p4 = pts4 + (size_t)n * PP;     // scalar base

    const int chunk  = (PP + 15) / 16;      // 314
    const int pstart = w * chunk;
    const int pend   = (pstart + chunk < PP) ? (pstart + chunk) : PP;

    unsigned int k0 = 0xFFFFFFFFu, k1 = 0xFFFFFFFFu, k2 = 0xFFFFFFFFu, k3 = 0xFFFFFFFFu;

#define INS(kb) { \
        unsigned int m2 = ((kb) > k2) ? (kb) : k2;  k3 = (k3 < m2) ? k3 : m2; \
        unsigned int m1 = ((kb) > k1) ? (kb) : k1;  k2 = (k2 < m1) ? k2 : m1; \
        unsigned int m0 = ((kb) > k0) ? (kb) : k0;  k1 = (k1 < m0) ? k1 : m0; \
        k0 = (k0 < (kb)) ? k0 : (kb); }

    int p = pstart;
    for (; p + 8 <= pend; p += 8) {
        float4 P[8];
#pragma unroll
        for (int j = 0; j < 8; ++j) P[j] = p4[p + j];
#pragma unroll
        for (int j = 0; j < 8; ++j) {
            const float dot = fmaf(cx, P[j].x, fmaf(cy, P[j].y, cz * P[j].z));
            float dd = fmaxf(fmaf(-2.0f, dot, cc + P[j].w), 0.f);
            const unsigned int kb = (__float_as_uint(dd) & 0xFFFFE000u) | (unsigned int)(p + j);
            INS(kb)
        }
    }
    for (; p < pend; ++p) {
        const float4 P = p4[p];
        const float dot = fmaf(cx, P.x, fmaf(cy, P.y, cz * P.z));
        float dd = fmaxf(fmaf(-2.0f, dot, cc + P.w), 0.f);
        const unsigned int kb = (__float_as_uint(dd) & 0xFFFFE000u) | (unsigned int)p;
        INS(kb)
    }

    KB[w][0][lane] = k0; KB[w][1][lane] = k1; KB[w][2][lane] = k2; KB[w][3][lane] = k3;
    __syncthreads();

    if (w == 0) {
        unsigned int s0 = 0xFFFFFFFFu, s1 = 0xFFFFFFFFu, s2 = 0xFFFFFFFFu, s3 = 0xFFFFFFFFu;
#pragma unroll
        for (int ww = 0; ww < 16; ++ww)
#pragma unroll
            for (int j = 0; j < 4; ++j) {
                const unsigned int kb = KB[ww][j][lane];
                unsigned int m2 = (kb > s2) ? kb : s2;  s3 = (s3 < m2) ? s3 : m2;
                unsigned int m1 = (kb > s1) ? kb : s1;  s2 = (s2 < m1) ? s2 : m1;
                unsigned int m0 = (kb > s0) ? kb : s0;  s1 = (s1 < m0) ? s1 : m0;
                s0 = (s0 < kb) ? s0 : kb;
            }
        const float* __restrict__ pb = pts + (size_t)n * PP * 3;
        int   id[4] = { (int)(s0 & 0x1FFFu), (int)(s1 & 0x1FFFu),
                        (int)(s2 & 0x1FFFu), (int)(s3 & 0x1FFFu) };
        float dv[4];
#pragma unroll
        for (int j = 0; j < 4; ++j) {
            const float px = pb[3*id[j]+0], py = pb[3*id[j]+1], pz = pb[3*id[j]+2];
            const float dt  = fmaf(cx, px, fmaf(cy, py, cz*pz));
            const float pp2 = fmaf(px, px, fmaf(py, py, pz*pz));
            dv[j] = fmaf(-2.0f, dt, cc + pp2);
        }
#define CSW(a,b) { bool sw = (dv[b] < dv[a]) || (dv[b] == dv[a] && id[b] < id[a]); \
                   if (sw) { float td=dv[a]; dv[a]=dv[b]; dv[b]=td; int ti=id[a]; id[a]=id[b]; id[b]=ti; } }
        CSW(0,1) CSW(2,3) CSW(0,2) CSW(1,3) CSW(1,2)
#undef CSW
        *(float4*)(odist + (size_t)q*4) = make_float4(dv[0], dv[1], dv[2], dv[3]);
        *(int4*)(oidx + (size_t)q*4)    = make_int4(id[0], id[1], id[2], id[3]);
    }
#undef INS
}

// ------------------------------------------------------------------
// per-(n,k) sum over m of 1/dist (deterministic)
__global__ __launch_bounds__(1024) void k_sums(const float* __restrict__ dist,
                                               float* __restrict__ sums) {
    const int b = blockIdx.x;            // n*4+k, 8 blocks
    const int n = b >> 2, k = b & 3;
    float s = 0.f;
    for (int m = threadIdx.x; m < MQ; m += 1024)
        s += 1.0f / dist[((size_t)n * MQ + m) * 4 + k];
    __shared__ float red[1024];
    red[threadIdx.x] = s;
    __syncthreads();
    for (int off = 512; off > 0; off >>= 1) {
        if (threadIdx.x < off) red[threadIdx.x] += red[threadIdx.x + off];
        __syncthreads();
    }
    if (threadIdx.x == 0) sums[b] = red[0];
}

// ------------------------------------------------------------------
// packed gemv: activations f16x2 from LDS (col = lane), weights f16x2 via
// wave-uniform s_load; fp32 accumulate via v_dot2_f32_f16.
template<int DIN2, int DOUT, int TILE>
__device__ __forceinline__ void gemv_p(const unsigned int* __restrict__ Xp, int lane,
                                       const unsigned int* __restrict__ Wp,
                                       const float* __restrict__ bias,
                                       int j0, float (&acc)[TILE]) {
#pragma unroll
    for (int u = 0; u < TILE; ++u) acc[u] = bias[j0 + u];
#pragma unroll
    for (int i2 = 0; i2 < DIN2; ++i2) {
        const unsigned int xv = Xp[i2 * 64 + lane];
        const unsigned int* wr = Wp + i2 * DOUT + j0;
#pragma unroll
        for (int u = 0; u < TILE; ++u) acc[u] = dot2(xv, wr[u], acc[u]);
    }
}

// harmonic value h of [sin(e) x12, cos(e) x12, r x3], e = r * 2^(h&3)
static __device__ __forceinline__ float harm_val(int h, float rx, float ry, float rz) {
    if (h >= 27) return 0.f;
    float v;
    if (h < 24) {
        int base = (h < 12) ? h : (h - 12);
        float rv = (base >> 2) == 0 ? rx : ((base >> 2) == 1 ? ry : rz);
        float e = rv * (float)(1 << (base & 3));
        v = (h < 12) ? sinf(e) : cosf(e);
    } else {
        v = (h == 24) ? rx : ((h == 25) ? ry : rz);
    }
    return v;
}

// ------------------------------------------------------------------
// main fused kernel v7: all 4 neighbors processed concurrently across waves.
// LDS (u32 rows of [64]): rows 0..119 x59 per k (k*30+r); rows 120..247 h1
// per k (120+k*32+r); rows 0..63 reused for wk-scaled p2 outputs (k*16+r);
// rows 128..159 feat; dense ping-pong rows 0..63 / 64..127; harm 128..141.
__global__ __launch_bounds__(1024, 2) void k_main(
    const float* __restrict__ coords, const float* __restrict__ dirs,
    const float* __restrict__ pts, const float* __restrict__ tex_raw,
    const float* __restrict__ tex_t, const float* __restrict__ emb,
    const unsigned int* __restrict__ wp,
    const float* __restrict__ pb1, const float* __restrict__ pb2,
    const float* __restrict__ fb1, const float* __restrict__ fb2,
    const float* __restrict__ fb3, const float* __restrict__ db,
    const float* __restrict__ rb1, const float* __restrict__ rb2,
    const int* __restrict__ idxbuf, const float* __restrict__ distbuf,
    const float* __restrict__ sums, float* __restrict__ out, int use_tex_t)
{
    __shared__ unsigned int S[248 * 64];   // 62 KB
    const int tid  = threadIdx.x;
    const int lane = tid & 63;
    const int wv   = __builtin_amdgcn_readfirstlane(tid >> 6);   // 0..15
    const int q0   = blockIdx.x * 64;
    const int n    = q0 >> 14;
    const int q    = q0 + lane;

    // ---------- phase 0: triplane sampling -> fp32 regs (2 ch/wave) ----------
    float tex_acc[2] = {0.f, 0.f};
    {
        const int g = wv;
        const float cx = coords[q*3+0], cy = coords[q*3+1], cz = coords[q*3+2];
#pragma unroll
        for (int pl = 0; pl < 3; ++pl) {
            float gx = (pl == 2) ? cz : cx;
            float gy = (pl == 0) ? cy : ((pl == 1) ? cz : cx);
            float x = (gx + 1.f) * 128.f - 0.5f;
            float y = (gy + 1.f) * 128.f - 0.5f;
            float x0f = floorf(x), y0f = floorf(y);
            float wx1 = x - x0f, wy1 = y - y0f;
            float wx0 = 1.f - wx1, wy0 = 1.f - wy1;
            int x0 = (int)x0f, y0 = (int)y0f;
            int n3 = n * 3 + pl;
            int  xs[4] = { x0, x0+1, x0,   x0+1 };
            int  ys[4] = { y0, y0,   y0+1, y0+1 };
            float wt[4] = { wx0*wy0, wx1*wy0, wx0*wy1, wx1*wy1 };
#pragma unroll
            for (int c = 0; c < 4; ++c) {
                int xi = xs[c], yi = ys[c];
                if (xi >= 0 && xi < HPX && yi >= 0 && yi < HPX) {
                    float wgt = wt[c];
                    if (use_tex_t) {
                        const float2 a = *(const float2*)(tex_t +
                            (((size_t)n3 * HWSZ + (size_t)yi * HPX + xi) * 32 + g * 2));
                        tex_acc[0] = fmaf(wgt, a.x, tex_acc[0]);
                        tex_acc[1] = fmaf(wgt, a.y, tex_acc[1]);
                    } else {
                        size_t base = ((size_t)(n3 * 32 + g * 2)) * HWSZ + (size_t)yi * HPX + xi;
                        tex_acc[0] = fmaf(wgt, tex_raw[base], tex_acc[0]);
                        tex_acc[1] = fmaf(wgt, tex_raw[base + HWSZ], tex_acc[1]);
                    }
                }
            }
        }
        tex_acc[0] *= (1.f / 3.f); tex_acc[1] *= (1.f / 3.f);
    }

    const int kk  = wv & 3;      // neighbor index this wave handles
    const int prt = wv >> 2;     // 0..3 part / j-slice

    // ---------- phase A: build x59 for ALL 4 neighbors (rows kk*30 + r) ----------
    {
        const int id = idxbuf[(size_t)q*4 + kk];
        const int rb = kk * 30;
        if (prt < 2) {
            // emb pairs: part0 rows 0..7 (ch0..15), part1 rows 8..15 (ch16..31)
#pragma unroll
            for (int t = 0; t < 2; ++t) {
                const float4 e = *(const float4*)(emb + (size_t)id * 32 + prt*16 + t*4 + 0)
                    , e2 = *(const float4*)(emb + (size_t)id * 32 + prt*16 + t*4 + 8);
                // rows rb + prt*8 + [t*2, t*2+1] and [t*2+4, t*2+5]
                S[(rb + prt*8 + t*2    )*64 + lane] = pk2(e.x,  e.y);
                S[(rb + prt*8 + t*2 + 1)*64 + lane] = pk2(e.z,  e.w);
                S[(rb + prt*8 + t*2 + 4)*64 + lane] = pk2(e2.x, e2.y);
                S[(rb + prt*8 + t*2 + 5)*64 + lane] = pk2(e2.z, e2.w);
            }
        } else {
            const float cx = coords[q*3+0], cy = coords[q*3+1], cz = coords[q*3+2];
            const float nx = pts[((size_t)n*PP + id)*3 + 0];
            const float ny = pts[((size_t)n*PP + id)*3 + 1];
            const float nz = pts[((size_t)n*PP + id)*3 + 2];
            float rx = cx - nx, ry = cy - ny, rz = cz - nz;
            float nrm = sqrtf(fmaf(rx, rx, fmaf(ry, ry, rz*rz)));
            float inv = 1.f / fmaxf(nrm, 1e-12f);
            rx *= inv; ry *= inv; rz *= inv;
            // harm pairs: part2 pairs 0..7 (h0..15) rows rb+16..23,
            //             part3 pairs 8..13 (h16..27) rows rb+24..29
            const int pr0 = (prt == 2) ? 0 : 8;
            const int prn = (prt == 2) ? 8 : 6;
#pragma unroll
            for (int t = 0; t < 8; ++t) {
                if (t < prn) {
                    int pr = pr0 + t;
                    S[(rb + 16 + pr)*64 + lane] =
                        pk2(harm_val(2*pr, rx, ry, rz), harm_val(2*pr + 1, rx, ry, rz));
                }
            }
        }
    }
    __syncthreads();

    // ---------- phase B: p1 59->64 relu for all k; wave (kk, j0=prt*16) ----------
    {
        float acc[16];
        gemv_p<30, 64, 16>(S + (kk*30)*64, lane, wp + WP_PW1, pb1, prt * 16, acc);
        const int rb = 120 + kk*32 + prt*8;
#pragma unroll
        for (int u = 0; u < 8; ++u)
            S[(rb + u)*64 + lane] = pk2(fmaxf(acc[2*u], 0.f), fmaxf(acc[2*u+1], 0.f));
    }
    __syncthreads();

    // ---------- phase C: p2 64->32 for all k, wk-scaled -> rows kk*16 + r ----------
    {
        float acc[8];
        gemv_p<32, 32, 8>(S + (120 + kk*32)*64, lane, wp + WP_PW2, pb2, prt * 8, acc);
        const float dist = distbuf[(size_t)q*4 + kk];
        const float wk = (1.0f / dist) / sums[n*4 + kk];
        const int rb = kk*16 + prt*4;
#pragma unroll
        for (int u = 0; u < 4; ++u)
            S[(rb + u)*64 + lane] = pk2(wk * acc[2*u], wk * acc[2*u+1]);
    }
    __syncthreads();

    // ---------- phase D: feat -> rows 128..159 (tex 128..143, pts 144..159) ----------
    {
        S[(128 + wv)*64 + lane] = pk2(tex_acc[0], tex_acc[1]);
        float a = 0.f, b = 0.f;
#pragma unroll
        for (int k = 0; k < 4; ++k) {
            float2 v = upk(S[(k*16 + wv)*64 + lane]);
            a += v.x; b += v.y;
        }
        S[(144 + wv)*64 + lane] = pk2(a, b);
    }
    __syncthreads();

    // ---------- phase E: fw1 64->128 relu, rows 128..159 -> rows 0..63 ----------
    {
        float acc[8];
        gemv_p<32, 128, 8>(S + 128*64, lane, wp + WP_FW1, fb1, wv * 8, acc);
#pragma unroll
        for (int u = 0; u < 4; ++u)
            S[(4*wv + u)*64 + lane] = pk2(fmaxf(acc[2*u], 0.f), fmaxf(acc[2*u+1], 0.f));
    }
    __syncthreads();
    // ---------- phase F: fw2 128->128 relu, rows 0..63 -> rows 64..127 ----------
    {
        float acc[8];
        gemv_p<64, 128, 8>(S, lane, wp + WP_FW2, fb2, wv * 8, acc);
#pragma unroll
        for (int u = 0; u < 4; ++u)
            S[(64 + 4*wv + u)*64 + lane] = pk2(fmaxf(acc[2*u], 0.f), fmaxf(acc[2*u+1], 0.f));
    }
    __syncthreads();
    // ---------- phase G: fw3 128->128, rows 64..127 -> rows 0..63 ----------
    {
        float acc[8];
        gemv_p<64, 128, 8>(S + 64*64, lane, wp + WP_FW3, fb3, wv * 8, acc);
#pragma unroll
        for (int u = 0; u < 4; ++u)
            S[(4*wv + u)*64 + lane] = pk2(acc[2*u], acc[2*u+1]);
    }
    __syncthreads();
    // ---------- phase H: ray harm -> rows 128..141 (waves 0..13); density (wave 15) ----------
    {
        if (wv < 14) {
            float dx = dirs[q*3+0], dy = dirs[q*3+1], dz = dirs[q*3+2];
            float dn = sqrtf(fmaf(dx, dx, fmaf(dy, dy, dz*dz)));
            float inv = 1.f / fmaxf(dn, 1e-12f);
            dx *= inv; dy *= inv; dz *= inv;
            S[(128 + wv)*64 + lane] = pk2(harm_val(2*wv, dx, dy, dz),
                                          harm_val(2*wv + 1, dx, dy, dz));
        } else if (wv == 15) {
            float z = db[0];
            const unsigned int* dwp = wp + WP_DW;
#pragma unroll
            for (int i2 = 0; i2 < 64; ++i2) z = dot2(S[i2*64 + lane], dwp[i2], z);
            const float cx = coords[q*3+0], cy = coords[q*3+1], cz = coords[q*3+2];
            float selv = (cx > -1.f && cx < 1.f && cy > -1.f && cy < 1.f &&
                          cz > -1.f && cz < 1.f) ? 1.f : 0.f;
            float t10 = 10.f * z;
            float sp = (t10 > 20.f) ? t10 : log1pf(expf(t10));
            float raw = sp * 0.1f * selv;
            out[q] = 1.f - expf(-raw);
        }
    }
    __syncthreads();
    // ---------- phase I: rw1 155->64 relu; feat rows 0..63 + harm 128..141 -> 64..95 ----------
    {
        const int j0 = wv * 4;
        float acc[4];
        gemv_p<64, 64, 4>(S, lane, wp + WP_RW1, rb1, j0, acc);
#pragma unroll
        for (int t = 0; t < 14; ++t) {
            const unsigned int xv = S[(128 + t)*64 + lane];
            const unsigned int* wr = wp + WP_RW1 + (64 + t) * 64 + j0;
#pragma unroll
            for (int u = 0; u < 4; ++u) acc[u] = dot2(xv, wr[u], acc[u]);
        }
        S[(64 + 2*wv    )*64 + lane] = pk2(fmaxf(acc[0], 0.f), fmaxf(acc[1], 0.f));
        S[(64 + 2*wv + 1)*64 + lane] = pk2(fmaxf(acc[2], 0.f), fmaxf(acc[3], 0.f));
    }
    __syncthreads();
    // ---------- phase J: rw2 64->32, sigmoid on first 3; rows 64..95 -> out ----------
    {
        float acc[2];
        gemv_p<32, 32, 2>(S + 64*64, lane, wp + WP_RW2, rb2, wv * 2, acc);
#pragma unroll
        for (int u = 0; u < 2; ++u) {
            int j = wv*2 + u;
            float v = acc[u];
            if (j < 3) v = 1.002f * (1.f / (1.f + expf(-v))) - 0.001f;
            out[OUT_RGB_OFF + (size_t)q*32 + j] = v;
        }
    }
}

// ------------------------------------------------------------------
extern "C" void kernel_launch(void* const* d_in, const int* in_sizes, int n_in,
                              void* d_out, int out_size, void* d_ws, size_t ws_size,
                              hipStream_t stream) {
    (void)in_sizes; (void)n_in; (void)out_size;
    const float* coords = (const float*)d_in[0];
    const float* dirs   = (const float*)d_in[1];
    const float* pts    = (const float*)d_in[2];
    const float* tex    = (const float*)d_in[3];
    const float* emb    = (const float*)d_in[4];
    const float* pw1 = (const float*)d_in[5];  const float* pb1 = (const float*)d_in[6];
    const float* pw2 = (const float*)d_in[7];  const float* pb2 = (const float*)d_in[8];
    const float* fw1 = (const float*)d_in[9];  const float* fb1 = (const float*)d_in[10];
    const float* fw2 = (const float*)d_in[11]; const float* fb2 = (const float*)d_in[12];
    const float* fw3 = (const float*)d_in[13]; const float* fb3 = (const float*)d_in[14];
    const float* dw  = (const float*)d_in[15]; const float* db  = (const float*)d_in[16];
    const float* rw1 = (const float*)d_in[17]; const float* rb1 = (const float*)d_in[18];
    const float* rw2 = (const float*)d_in[19]; const float* rb2 = (const float*)d_in[20];

    float*        out    = (float*)d_out;
    int*          wsidx  = (int*)d_ws;
    float*        wssums = (float*)((char*)d_ws + WS_SUMS_OFF);
    float4*       wspts4 = (float4*)((char*)d_ws + WS_PTS4_OFF);
    unsigned int* wswp   = (unsigned int*)((char*)d_ws + WS_WP_OFF);
    float*        wstex  = (float*)((char*)d_ws + WS_TEX_OFF);

    const size_t need_tex = WS_TEX_OFF + (size_t)6 * HWSZ * 32 * 4;
    const int use_t = (ws_size >= need_tex) ? 1 : 0;

    PackArgs pa;
    pa.src[0] = pw1; pa.off[0] = WP_PW1; pa.din[0] = 59;  pa.dout[0] = 64;
    pa.src[1] = pw2; pa.off[1] = WP_PW2; pa.din[1] = 64;  pa.dout[1] = 32;
    pa.src[2] = fw1; pa.off[2] = WP_FW1; pa.din[2] = 64;  pa.dout[2] = 128;
    pa.src[3] = fw2; pa.off[3] = WP_FW2; pa.din[3] = 128; pa.dout[3] = 128;
    pa.src[4] = fw3; pa.off[4] = WP_FW3; pa.din[4] = 128; pa.dout[4] = 128;
    pa.src[5] = dw;  pa.off[5] = WP_DW;  pa.din[5] = 128; pa.dout[5] = 1;
    pa.src[6] = rw1; pa.off[6] = WP_RW1; pa.din[6] = 155; pa.dout[6] = 64;
    pa.src[7] = rw2; pa.off[7] = WP_RW2; pa.din[7] = 64;  pa.dout[7] = 32;

    k_pack<<<dim3(32, 8), 256, 0, stream>>>(pa, wswp);
    k_pts4<<<(NB*PP + 255)/256, 256, 0, stream>>>(pts, wspts4);
    if (use_t) k_transpose<<<6 * 256, 256, 0, stream>>>(tex, wstex);
    k_knn<<<NQ / 64, 1024, 0, stream>>>(coords, wspts4, pts, out + OUT_DIST_OFF, wsidx);
    k_sums<<<8, 1024, 0, stream>>>(out + OUT_DIST_OFF, wssums);
    k_main<<<NQ / 64, 1024, 0, stream>>>(coords, dirs, pts, tex, wstex, emb,
                                         wswp, pb1, pb2, fb1, fb2, fb3, db, rb1, rb2,
                                         wsidx, out + OUT_DIST_OFF, wssums, out, use_t);
}

// Round 8
// 329.111 us; speedup vs baseline: 1.5245x; 1.0040x over previous
//
#include <hip/hip_runtime.h>
#include <float.h>
#include <math.h>

#define NB 2
#define MQ 16384
#define NQ (NB*MQ)          // 32768 queries
#define PP 5023
#define KNN 4
#define HPX 256
#define HWSZ (HPX*HPX)      // 65536

// output layout (floats): densities[NQ], rgb[NQ*32], dist[NQ*4]
#define OUT_RGB_OFF  ((size_t)NQ)
#define OUT_DIST_OFF ((size_t)NQ + (size_t)NQ*32)

// workspace layout (bytes)
#define WS_SUMS_OFF ((size_t)NQ*KNN*4)       // 512 KB: 8 floats
#define WS_PTS4_OFF ((size_t)0x90000)        // 576 KB: 2*5023*16 B
#define WS_WP_OFF   ((size_t)0xC0000)        // 768 KB: 29504 u32 = 118 KB
#define WS_TEX_OFF  ((size_t)1<<20)          // 1 MB: 48 MB transposed tex

// packed-weight sub-offsets (u32 units)
#define WP_PW1 0
#define WP_PW2 1920
#define WP_FW1 2944
#define WP_FW2 7040
#define WP_FW3 15232
#define WP_DW  23424
#define WP_RW1 23488
#define WP_RW2 28480

typedef __attribute__((ext_vector_type(2))) _Float16 half2v;

static __device__ __forceinline__ unsigned int pk2(float a, float b) {
    half2v h; h[0] = (_Float16)a; h[1] = (_Float16)b;   // RNE converts
    return __builtin_bit_cast(unsigned int, h);
}
static __device__ __forceinline__ float2 upk(unsigned int u) {
    half2v h = __builtin_bit_cast(half2v, u);
    return make_float2((float)h[0], (float)h[1]);
}
static __device__ __forceinline__ float dot2(unsigned int a, unsigned int b, float c) {
    return __builtin_amdgcn_fdot2(__builtin_bit_cast(half2v, a),
                                  __builtin_bit_cast(half2v, b), c, false);
}

// ------------------------------------------------------------------
// weight pack: fp32 [DIN][DOUT] -> f16x2 [(DIN+1)/2][DOUT] (pairs across DIN)
struct PackArgs {
    const float* src[8];
    int off[8]; int din[8]; int dout[8];
};
__global__ __launch_bounds__(256) void k_pack(PackArgs a, unsigned int* wp) {
    const int mid = blockIdx.y;
    const int idx = blockIdx.x * 256 + threadIdx.x;
    const int DIN = a.din[mid], DOUT = a.dout[mid];
    const int din2 = (DIN + 1) >> 1;
    if (idx >= din2 * DOUT) return;
    const int i2 = idx / DOUT, j = idx - i2 * DOUT;
    const float* s = a.src[mid];
    const float lo = s[(2*i2) * DOUT + j];
    const float hi = (2*i2 + 1 < DIN) ? s[(2*i2 + 1) * DOUT + j] : 0.f;
    wp[a.off[mid] + idx] = pk2(lo, hi);
}

// pts4 = (x, y, z, |p|^2)
__global__ __launch_bounds__(256) void k_pts4(const float* __restrict__ pts,
                                              float4* __restrict__ o) {
    const int i = blockIdx.x * 256 + threadIdx.x;
    if (i >= NB * PP) return;
    const float px = pts[3*i], py = pts[3*i+1], pz = pts[3*i+2];
    o[i] = make_float4(px, py, pz, fmaf(px, px, fmaf(py, py, pz*pz)));
}

// ------------------------------------------------------------------
// texture transpose: [n3][32][HW] -> [n3][HW][32]
__global__ __launch_bounds__(256) void k_transpose(const float* __restrict__ src,
                                                   float* __restrict__ dst) {
    const int tid = threadIdx.x;
    const int b = blockIdx.x;            // 6*256 blocks
    const int n3 = b >> 8;
    const int hw = ((b & 255) << 8) + tid;
    const float* s = src + (size_t)n3 * 32 * HWSZ + hw;
    float v[32];
#pragma unroll
    for (int c = 0; c < 32; ++c) v[c] = s[(size_t)c * HWSZ];
    float4* d = (float4*)(dst + ((size_t)n3 * HWSZ + hw) * 32);
#pragma unroll
    for (int c = 0; c < 8; ++c) d[c] = make_float4(v[4*c], v[4*c+1], v[4*c+2], v[4*c+3]);
}

// ------------------------------------------------------------------
// KNN v7: 16 waves/block = 64 queries; points staged into LDS via VECTOR
// loads (2 passes x 40 KB), scanned with broadcast ds_read_b128 -> no
// scalar-cache miss serialization.
#define KCHUNK 2560
__global__ __launch_bounds__(1024, 2) void k_knn(const float* __restrict__ coords,
                                                 const float4* __restrict__ pts4,
                                                 const float* __restrict__ pts,
                                                 float* __restrict__ odist,
                                                 int* __restrict__ oidx) {
    __shared__ float4 SP[KCHUNK];            // 40 KB
    __shared__ unsigned int KB[16][4][64];   // 16 KB
    const int tid  = threadIdx.x;
    const int lane = tid & 63;
    const int w    = __builtin_amdgcn_readfirstlane(tid >> 6);  // 0..15
    const int q0   = blockIdx.x * 64;       // 512 blocks
    const int q    = q0 + lane;
    const int n    = q0 >> 14;              // scalar
    const float cx = coords[q*3+0], cy = coords[q*3+1], cz = coords[q*3+2];
    const float cc = fmaf(cx, cx, fmaf(cy, cy, cz*cz));
    const float4* __restrict__ p4 = pts4 + (size_t)n * PP;

    unsigned int k0 = 0xFFFFFFFFu, k1 = 0xFFFFFFFFu, k2 = 0xFFFFFFFFu, k3 = 0xFFFFFFFFu;

#define INS(kb) { \
        unsigned int m2 = ((kb) > k2) ? (kb) : k2;  k3 = (k3 < m2) ? k3 : m2; \
        unsigned int m1 = ((kb) > k1) ? (kb) : k1;  k2 = (k2 < m1) ? k2 : m1; \
        unsigned int m0 = ((kb) > k0) ? (kb) : k0;  k1 = (k1 < m0) ? k1 : m0; \
        k0 = (k0 < (kb)) ? k0 : (kb); }

#pragma unroll 1
    for (int half = 0; half < 2; ++half) {
        const int base = half * KCHUNK;
        const int cnt  = (PP - base < KCHUNK) ? (PP - base) : KCHUNK;
        __syncthreads();                    // protect SP reuse
        for (int i = tid; i < cnt; i += 1024) SP[i] = p4[base + i];
        __syncthreads();
        const int per = (cnt + 15) >> 4;
        const int s0 = w * per;
        const int s1 = (s0 + per < cnt) ? (s0 + per) : cnt;
#pragma unroll 4
        for (int j = s0; j < s1; ++j) {
            const float4 P = SP[j];                      // broadcast ds_read
            const float dot = fmaf(cx, P.x, fmaf(cy, P.y, cz * P.z));
            float dd = fmaxf(fmaf(-2.0f, dot, cc + P.w), 0.f);
            const unsigned int kb = (__float_as_uint(dd) & 0xFFFFE000u)
                                    | (unsigned int)(base + j);
            INS(kb)
        }
    }
#undef INS

    KB[w][0][lane] = k0; KB[w][1][lane] = k1; KB[w][2][lane] = k2; KB[w][3][lane] = k3;
    __syncthreads();

    if (w == 0) {
        unsigned int s0 = 0xFFFFFFFFu, s1 = 0xFFFFFFFFu, s2 = 0xFFFFFFFFu, s3 = 0xFFFFFFFFu;
#pragma unroll
        for (int ww = 0; ww < 16; ++ww)
#pragma unroll
            for (int j = 0; j < 4; ++j) {
                const unsigned int kb = KB[ww][j][lane];
                unsigned int m2 = (kb > s2) ? kb : s2;  s3 = (s3 < m2) ? s3 : m2;
                unsigned int m1 = (kb > s1) ? kb : s1;  s2 = (s2 < m1) ? s2 : m1;
                unsigned int m0 = (kb > s0) ? kb : s0;  s1 = (s1 < m0) ? s1 : m0;
                s0 = (s0 < kb) ? s0 : kb;
            }
        const float* __restrict__ pb = pts + (size_t)n * PP * 3;
        int   id[4] = { (int)(s0 & 0x1FFFu), (int)(s1 & 0x1FFFu),
                        (int)(s2 & 0x1FFFu), (int)(s3 & 0x1FFFu) };
        float dv[4];
#pragma unroll
        for (int j = 0; j < 4; ++j) {
            const float px = pb[3*id[j]+0], py = pb[3*id[j]+1], pz = pb[3*id[j]+2];
            const float dt  = fmaf(cx, px, fmaf(cy, py, cz*pz));
            const float pp2 = fmaf(px, px, fmaf(py, py, pz*pz));
            dv[j] = fmaf(-2.0f, dt, cc + pp2);
        }
#define CSW(a,b) { bool sw = (dv[b] < dv[a]) || (dv[b] == dv[a] && id[b] < id[a]); \
                   if (sw) { float td=dv[a]; dv[a]=dv[b]; dv[b]=td; int ti=id[a]; id[a]=id[b]; id[b]=ti; } }
        CSW(0,1) CSW(2,3) CSW(0,2) CSW(1,3) CSW(1,2)
#undef CSW
        *(float4*)(odist + (size_t)q*4) = make_float4(dv[0], dv[1], dv[2], dv[3]);
        *(int4*)(oidx + (size_t)q*4)    = make_int4(id[0], id[1], id[2], id[3]);
    }
}

// ------------------------------------------------------------------
// per-(n,k) sum over m of 1/dist (deterministic)
__global__ __launch_bounds__(1024) void k_sums(const float* __restrict__ dist,
                                               float* __restrict__ sums) {
    const int b = blockIdx.x;            // n*4+k, 8 blocks
    const int n = b >> 2, k = b & 3;
    float s = 0.f;
    for (int m = threadIdx.x; m < MQ; m += 1024)
        s += 1.0f / dist[((size_t)n * MQ + m) * 4 + k];
    __shared__ float red[1024];
    red[threadIdx.x] = s;
    __syncthreads();
    for (int off = 512; off > 0; off >>= 1) {
        if (threadIdx.x < off) red[threadIdx.x] += red[threadIdx.x + off];
        __syncthreads();
    }
    if (threadIdx.x == 0) sums[b] = red[0];
}

// ------------------------------------------------------------------
// gemv with bias: activations f16x2 from LDS (col=lane), weights f16x2 from
// LDS via broadcast ds_read (wave-uniform address).
template<int DIN2, int DOUT, int TILE>
__device__ __forceinline__ void gemv_p(const unsigned int* Xp, int lane,
                                       const unsigned int* Wl,
                                       const float* __restrict__ bias,
                                       int j0, float (&acc)[TILE]) {
#pragma unroll
    for (int u = 0; u < TILE; ++u) acc[u] = bias[j0 + u];
#pragma unroll
    for (int i2 = 0; i2 < DIN2; ++i2) {
        const unsigned int xv = Xp[i2 * 64 + lane];
        const unsigned int* wr = Wl + i2 * DOUT + j0;
#pragma unroll
        for (int u = 0; u < TILE; ++u) acc[u] = dot2(xv, wr[u], acc[u]);
    }
}
// partial-K accumulate (no bias)
template<int DIN2, int DOUT, int TILE>
__device__ __forceinline__ void gemv_acc(const unsigned int* Xp, int lane,
                                         const unsigned int* Wl,
                                         int j0, float (&acc)[TILE]) {
#pragma unroll
    for (int i2 = 0; i2 < DIN2; ++i2) {
        const unsigned int xv = Xp[i2 * 64 + lane];
        const unsigned int* wr = Wl + i2 * DOUT + j0;
#pragma unroll
        for (int u = 0; u < TILE; ++u) acc[u] = dot2(xv, wr[u], acc[u]);
    }
}

// harmonic value h of [sin x12, cos x12, r x3]
static __device__ __forceinline__ float harm_val(int h, float rx, float ry, float rz) {
    if (h >= 27) return 0.f;
    float v;
    if (h < 24) {
        int base = (h < 12) ? h : (h - 12);
        float rv = (base >> 2) == 0 ? rx : ((base >> 2) == 1 ? ry : rz);
        float e = rv * (float)(1 << (base & 3));
        v = (h < 12) ? sinf(e) : cosf(e);
    } else {
        v = (h == 24) ? rx : ((h == 25) ? ry : rz);
    }
    return v;
}

// ------------------------------------------------------------------
// main fused kernel v8: LDS-staged weight windows (WBa/WBb, 8 KB each),
// staged one window ahead via coalesced vector loads; broadcast ds_read
// weights in every gemv. Neighbors in 2 passes of 2. LDS = 64,512 B.
//
// S row map (u32 rows of [64]):
//   0..63   p2out (k*16+r) -> later fw2-out / rw1-out (rows 0..31)
//   64..95  feat (tex 64..79, pts 80..95) -> later ray-harm rows 64..77
//   64..123 x59 pair (64 + kk2*30 + r)    [before feat]
//   96..159 fw1-out / fw3-out (dense0)
//   124..187 h1 pair (124 + kk2*32 + r)
__global__ __launch_bounds__(1024, 2) void k_main(
    const float* __restrict__ coords, const float* __restrict__ dirs,
    const float* __restrict__ pts, const float* __restrict__ tex_raw,
    const float* __restrict__ tex_t, const float* __restrict__ emb,
    const unsigned int* __restrict__ wp,
    const float* __restrict__ pb1, const float* __restrict__ pb2,
    const float* __restrict__ fb1, const float* __restrict__ fb2,
    const float* __restrict__ fb3, const float* __restrict__ db,
    const float* __restrict__ rb1, const float* __restrict__ rb2,
    const int* __restrict__ idxbuf, const float* __restrict__ distbuf,
    const float* __restrict__ sums, float* __restrict__ out, int use_tex_t)
{
    __shared__ unsigned int S[188 * 64];   // 48,128 B
    __shared__ unsigned int WBa[2048];     // 8 KB weight window A
    __shared__ unsigned int WBb[2048];     // 8 KB weight window B
    const int tid  = threadIdx.x;
    const int lane = tid & 63;
    const int wv   = __builtin_amdgcn_readfirstlane(tid >> 6);   // 0..15
    const int q0   = blockIdx.x * 64;
    const int n    = q0 >> 14;
    const int q    = q0 + lane;

    unsigned int pa0, pa1, pb0_, pb1_;     // prefetch regs (a/b bound)

    // ---------- tex sampling -> fp32 regs (2 ch/wave) ----------
    float tex_acc[2] = {0.f, 0.f};
    {
        const int g = wv;
        const float cx = coords[q*3+0], cy = coords[q*3+1], cz = coords[q*3+2];
#pragma unroll
        for (int pl = 0; pl < 3; ++pl) {
            float gx = (pl == 2) ? cz : cx;
            float gy = (pl == 0) ? cy : ((pl == 1) ? cz : cx);
            float x = (gx + 1.f) * 128.f - 0.5f;
            float y = (gy + 1.f) * 128.f - 0.5f;
            float x0f = floorf(x), y0f = floorf(y);
            float wx1 = x - x0f, wy1 = y - y0f;
            float wx0 = 1.f - wx1, wy0 = 1.f - wy1;
            int x0 = (int)x0f, y0 = (int)y0f;
            int n3 = n * 3 + pl;
            int  xs[4] = { x0, x0+1, x0,   x0+1 };
            int  ys[4] = { y0, y0,   y0+1, y0+1 };
            float wt[4] = { wx0*wy0, wx1*wy0, wx0*wy1, wx1*wy1 };
#pragma unroll
            for (int c = 0; c < 4; ++c) {
                int xi = xs[c], yi = ys[c];
                if (xi >= 0 && xi < HPX && yi >= 0 && yi < HPX) {
                    float wgt = wt[c];
                    if (use_tex_t) {
                        const float2 a = *(const float2*)(tex_t +
                            (((size_t)n3 * HWSZ + (size_t)yi * HPX + xi) * 32 + g * 2));
                        tex_acc[0] = fmaf(wgt, a.x, tex_acc[0]);
                        tex_acc[1] = fmaf(wgt, a.y, tex_acc[1]);
                    } else {
                        size_t base = ((size_t)(n3 * 32 + g * 2)) * HWSZ + (size_t)yi * HPX + xi;
                        tex_acc[0] = fmaf(wgt, tex_raw[base], tex_acc[0]);
                        tex_acc[1] = fmaf(wgt, tex_raw[base + HWSZ], tex_acc[1]);
                    }
                }
            }
        }
        tex_acc[0] *= (1.f / 3.f); tex_acc[1] *= (1.f / 3.f);
    }

#define PF_LOAD(r0, r1, off, len) { \
        r0 = (tid < (len)) ? wp[(off) + tid] : 0u; \
        r1 = (tid + 1024 < (len)) ? wp[(off) + tid + 1024] : 0u; }
#define PF_STORE(buf, r0, r1, len) { \
        if (tid < (len)) buf[tid] = r0; \
        if (tid + 1024 < (len)) buf[tid + 1024] = r1; }

    const int kk2 = wv & 1;     // neighbor within pair
    const int sl  = wv >> 1;    // 0..7 slice

    // phase-A builder for pass pp
#define PHASE_A(pp) { \
        const int k = (pp)*2 + kk2; \
        const int id = idxbuf[(size_t)q*4 + k]; \
        const int xb = 64 + kk2*30; \
        if (sl < 4) { \
            const float4 e0 = *(const float4*)(emb + (size_t)id * 32 + sl*8); \
            const float4 e1 = *(const float4*)(emb + (size_t)id * 32 + sl*8 + 4); \
            S[(xb + sl*4 + 0)*64 + lane] = pk2(e0.x, e0.y); \
            S[(xb + sl*4 + 1)*64 + lane] = pk2(e0.z, e0.w); \
            S[(xb + sl*4 + 2)*64 + lane] = pk2(e1.x, e1.y); \
            S[(xb + sl*4 + 3)*64 + lane] = pk2(e1.z, e1.w); \
        } else { \
            const float cx = coords[q*3+0], cy = coords[q*3+1], cz = coords[q*3+2]; \
            const float nx = pts[((size_t)n*PP + id)*3 + 0]; \
            const float ny = pts[((size_t)n*PP + id)*3 + 1]; \
            const float nz = pts[((size_t)n*PP + id)*3 + 2]; \
            float rx = cx - nx, ry = cy - ny, rz = cz - nz; \
            float nrm = sqrtf(fmaf(rx, rx, fmaf(ry, ry, rz*rz))); \
            float inv = 1.f / fmaxf(nrm, 1e-12f); \
            rx *= inv; ry *= inv; rz *= inv; \
            const int pr0 = (sl == 4) ? 0 : (sl == 5) ? 4 : (sl == 6) ? 8 : 11; \
            const int prn = (sl <= 5) ? 4 : 3; \
            for (int t = 0; t < 4; ++t) if (t < prn) { \
                int pr = pr0 + t; \
                S[(xb + 16 + pr)*64 + lane] = \
                    pk2(harm_val(2*pr, rx, ry, rz), harm_val(2*pr + 1, rx, ry, rz)); \
            } \
        } }

#define PHASE_B() { \
        float acc[8]; \
        gemv_p<30, 64, 8>(S + (64 + kk2*30)*64, lane, WBa, pb1, sl*8, acc); \
        const int rb = 124 + kk2*32 + sl*4; \
        for (int u = 0; u < 4; ++u) \
            S[(rb + u)*64 + lane] = pk2(fmaxf(acc[2*u], 0.f), fmaxf(acc[2*u+1], 0.f)); }

#define PHASE_C(pp) { \
        float acc[4]; \
        gemv_p<32, 32, 4>(S + (124 + kk2*32)*64, lane, WBb, pb2, sl*4, acc); \
        const int k = (pp)*2 + kk2; \
        const float dist = distbuf[(size_t)q*4 + k]; \
        const float wk = (1.0f / dist) / sums[n*4 + k]; \
        const int rb = k*16 + sl*2; \
        S[(rb + 0)*64 + lane] = pk2(wk * acc[0], wk * acc[1]); \
        S[(rb + 1)*64 + lane] = pk2(wk * acc[2], wk * acc[3]); }

    // ---------------- pipeline ----------------
    PF_LOAD(pa0, pa1, WP_PW1, 1920)                    // S1 pw1
    // W1: A1
    PHASE_A(0)
    PF_STORE(WBa, pa0, pa1, 1920)
    PF_LOAD(pb0_, pb1_, WP_PW2, 1024)                  // S2 pw2
    __syncthreads();
    // W2: B1
    PHASE_B()
    PF_STORE(WBb, pb0_, pb1_, 1024)
    PF_LOAD(pa0, pa1, WP_FW1, 2048)                    // S3 fw1h1
    __syncthreads();
    // W3: C1 + A2
    PHASE_C(0)
    PHASE_A(1)
    __syncthreads();
    // W4: B2
    PHASE_B()
    PF_LOAD(pb0_, pb1_, WP_FW1 + 2048, 2048)           // S4 fw1h2
    __syncthreads();
    // W5: C2
    PHASE_C(1)
    PF_STORE(WBa, pa0, pa1, 2048)                      // S3
    __syncthreads();
    // W6: D (feat)
    {
        S[(64 + wv)*64 + lane] = pk2(tex_acc[0], tex_acc[1]);
        float a = 0.f, b = 0.f;
#pragma unroll
        for (int k = 0; k < 4; ++k) {
            float2 v = upk(S[(k*16 + wv)*64 + lane]);
            a += v.x; b += v.y;
        }
        S[(80 + wv)*64 + lane] = pk2(a, b);
    }
    PF_STORE(WBb, pb0_, pb1_, 2048)                    // S4
    PF_LOAD(pa0, pa1, WP_FW2, 2048)                    // S5 fw2q1
    __syncthreads();
    // W7: E1 (fw1 K-half 1)
    float accE[8];
#pragma unroll
    for (int u = 0; u < 8; ++u) accE[u] = fb1[wv*8 + u];
    gemv_acc<16, 128, 8>(S + 64*64, lane, WBa, wv*8, accE);
    PF_LOAD(pb0_, pb1_, WP_FW2 + 2048, 2048)           // S6 fw2q2
    __syncthreads();
    // W8: E2 (fw1 K-half 2) -> dense0 rows 96..159
    gemv_acc<16, 128, 8>(S + 80*64, lane, WBb, wv*8, accE);
#pragma unroll
    for (int u = 0; u < 4; ++u)
        S[(96 + wv*4 + u)*64 + lane] = pk2(fmaxf(accE[2*u], 0.f), fmaxf(accE[2*u+1], 0.f));
    PF_STORE(WBa, pa0, pa1, 2048)                      // S5
    __syncthreads();
    // W9..W12: fw2 quarters -> dense1 rows 0..63
    float accF[8];
#pragma unroll
    for (int u = 0; u < 8; ++u) accF[u] = fb2[wv*8 + u];
    gemv_acc<16, 128, 8>(S + 96*64, lane, WBa, wv*8, accF);        // F1
    PF_STORE(WBb, pb0_, pb1_, 2048)                    // S6
    PF_LOAD(pa0, pa1, WP_FW2 + 4096, 2048)             // S7
    __syncthreads();
    gemv_acc<16, 128, 8>(S + 112*64, lane, WBb, wv*8, accF);       // F2
    PF_STORE(WBa, pa0, pa1, 2048)                      // S7
    PF_LOAD(pb0_, pb1_, WP_FW2 + 6144, 2048)           // S8
    __syncthreads();
    gemv_acc<16, 128, 8>(S + 128*64, lane, WBa, wv*8, accF);       // F3
    PF_STORE(WBb, pb0_, pb1_, 2048)                    // S8
    PF_LOAD(pa0, pa1, WP_FW3, 2048)                    // S9
    __syncthreads();
    gemv_acc<16, 128, 8>(S + 144*64, lane, WBb, wv*8, accF);       // F4
#pragma unroll
    for (int u = 0; u < 4; ++u)
        S[(wv*4 + u)*64 + lane] = pk2(fmaxf(accF[2*u], 0.f), fmaxf(accF[2*u+1], 0.f));
    PF_STORE(WBa, pa0, pa1, 2048)                      // S9
    PF_LOAD(pb0_, pb1_, WP_FW3 + 2048, 2048)           // S10
    __syncthreads();
    // W13..W16: fw3 quarters -> dense0 rows 96..159 (+ ray harm at W16)
    float accG[8];
#pragma unroll
    for (int u = 0; u < 8; ++u) accG[u] = fb3[wv*8 + u];
    gemv_acc<16, 128, 8>(S + 0*64, lane, WBa, wv*8, accG);         // G1
    PF_STORE(WBb, pb0_, pb1_, 2048)                    // S10
    PF_LOAD(pa0, pa1, WP_FW3 + 4096, 2048)             // S11
    __syncthreads();
    gemv_acc<16, 128, 8>(S + 16*64, lane, WBb, wv*8, accG);        // G2
    PF_STORE(WBa, pa0, pa1, 2048)                      // S11
    PF_LOAD(pb0_, pb1_, WP_FW3 + 6144, 2048)           // S12
    __syncthreads();
    gemv_acc<16, 128, 8>(S + 32*64, lane, WBa, wv*8, accG);        // G3
    PF_STORE(WBb, pb0_, pb1_, 2048)                    // S12
    PF_LOAD(pa0, pa1, WP_RW1, 1664)                    // S13 rw1 t1
    __syncthreads();
    gemv_acc<16, 128, 8>(S + 48*64, lane, WBb, wv*8, accG);        // G4
#pragma unroll
    for (int u = 0; u < 4; ++u)
        S[(96 + wv*4 + u)*64 + lane] = pk2(accG[2*u], accG[2*u+1]);
    if (wv < 14) {                                     // ray harmonics rows 64..77
        float dx = dirs[q*3+0], dy = dirs[q*3+1], dz = dirs[q*3+2];
        float dn = sqrtf(fmaf(dx, dx, fmaf(dy, dy, dz*dz)));
        float inv = 1.f / fmaxf(dn, 1e-12f);
        dx *= inv; dy *= inv; dz *= inv;
        S[(64 + wv)*64 + lane] = pk2(harm_val(2*wv, dx, dy, dz),
                                     harm_val(2*wv + 1, dx, dy, dz));
    }
    PF_STORE(WBa, pa0, pa1, 1664)                      // S13
    PF_LOAD(pb0_, pb1_, WP_RW1 + 1664, 1664)           // S14 rw1 t2
    __syncthreads();
    // W17..W19: rw1 thirds -> rows 0..31
    const int j0r = wv * 4;
    float accI[4];
#pragma unroll
    for (int u = 0; u < 4; ++u) accI[u] = rb1[j0r + u];
#pragma unroll 1
    for (int i2 = 0; i2 < 26; ++i2) {                  // I1: k2 0..25
        const unsigned int xv = S[(96 + i2)*64 + lane];
        const unsigned int* wr = WBa + i2*64 + j0r;
#pragma unroll
        for (int u = 0; u < 4; ++u) accI[u] = dot2(xv, wr[u], accI[u]);
    }
    PF_STORE(WBb, pb0_, pb1_, 1664)                    // S14
    PF_LOAD(pa0, pa1, WP_RW1 + 3328, 1664)             // S15 rw1 t3
    __syncthreads();
#pragma unroll 1
    for (int i2 = 26; i2 < 52; ++i2) {                 // I2: k2 26..51
        const unsigned int xv = S[(96 + i2)*64 + lane];
        const unsigned int* wr = WBb + (i2 - 26)*64 + j0r;
#pragma unroll
        for (int u = 0; u < 4; ++u) accI[u] = dot2(xv, wr[u], accI[u]);
    }
    PF_STORE(WBa, pa0, pa1, 1664)                      // S15
    PF_LOAD(pb0_, pb1_, WP_RW2, 1024)                  // S16a rw2
    unsigned int pd0 = (tid < 64) ? wp[WP_DW + tid] : 0u;  // S16b dw
    __syncthreads();
#pragma unroll 1
    for (int i2 = 52; i2 < 78; ++i2) {                 // I3: k2 52..77
        const int xr = (i2 < 64) ? (96 + i2) : (64 + (i2 - 64));
        const unsigned int xv = S[xr*64 + lane];
        const unsigned int* wr = WBa + (i2 - 52)*64 + j0r;
#pragma unroll
        for (int u = 0; u < 4; ++u) accI[u] = dot2(xv, wr[u], accI[u]);
    }
    S[(wv*2 + 0)*64 + lane] = pk2(fmaxf(accI[0], 0.f), fmaxf(accI[1], 0.f));
    S[(wv*2 + 1)*64 + lane] = pk2(fmaxf(accI[2], 0.f), fmaxf(accI[3], 0.f));
    PF_STORE(WBb, pb0_, pb1_, 1024)                    // S16a
    if (tid < 64) WBb[1024 + tid] = pd0;               // S16b
    __syncthreads();
    // W20: J (rw2 + sigmoid) and density (wave 15)
    {
        float acc[2];
        gemv_p<32, 32, 2>(S, lane, WBb, rb2, wv*2, acc);
#pragma unroll
        for (int u = 0; u < 2; ++u) {
            int j = wv*2 + u;
            float v = acc[u];
            if (j < 3) v = 1.002f * (1.f / (1.f + expf(-v))) - 0.001f;
            out[OUT_RGB_OFF + (size_t)q*32 + j] = v;
        }
        if (wv == 15) {
            float z = db[0];
#pragma unroll 1
            for (int i2 = 0; i2 < 64; ++i2)
                z = dot2(S[(96 + i2)*64 + lane], WBb[1024 + i2], z);
            const float cx = coords[q*3+0], cy = coords[q*3+1], cz = coords[q*3+2];
            float selv = (cx > -1.f && cx < 1.f && cy > -1.f && cy < 1.f &&
                          cz > -1.f && cz < 1.f) ? 1.f : 0.f;
            float t10 = 10.f * z;
            float sp = (t10 > 20.f) ? t10 : log1pf(expf(t10));
            float raw = sp * 0.1f * selv;
            out[q] = 1.f - expf(-raw);
        }
    }
#undef PF_LOAD
#undef PF_STORE
#undef PHASE_A
#undef PHASE_B
#undef PHASE_C
}

// ------------------------------------------------------------------
extern "C" void kernel_launch(void* const* d_in, const int* in_sizes, int n_in,
                              void* d_out, int out_size, void* d_ws, size_t ws_size,
                              hipStream_t stream) {
    (void)in_sizes; (void)n_in; (void)out_size;
    const float* coords = (const float*)d_in[0];
    const float* dirs   = (const float*)d_in[1];
    const float* pts    = (const float*)d_in[2];
    const float* tex    = (const float*)d_in[3];
    const float* emb    = (const float*)d_in[4];
    const float* pw1 = (const float*)d_in[5];  const float* pb1 = (const float*)d_in[6];
    const float* pw2 = (const float*)d_in[7];  const float* pb2 = (const float*)d_in[8];
    const float* fw1 = (const float*)d_in[9];  const float* fb1 = (const float*)d_in[10];
    const float* fw2 = (const float*)d_in[11]; const float* fb2 = (const float*)d_in[12];
    const float* fw3 = (const float*)d_in[13]; const float* fb3 = (const float*)d_in[14];
    const float* dw  = (const float*)d_in[15]; const float* db  = (const float*)d_in[16];
    const float* rw1 = (const float*)d_in[17]; const float* rb1 = (const float*)d_in[18];
    const float* rw2 = (const float*)d_in[19]; const float* rb2 = (const float*)d_in[20];

    float*        out    = (float*)d_out;
    int*          wsidx  = (int*)d_ws;
    float*        wssums = (float*)((char*)d_ws + WS_SUMS_OFF);
    float4*       wspts4 = (float4*)((char*)d_ws + WS_PTS4_OFF);
    unsigned int* wswp   = (unsigned int*)((char*)d_ws + WS_WP_OFF);
    float*        wstex  = (float*)((char*)d_ws + WS_TEX_OFF);

    const size_t need_tex = WS_TEX_OFF + (size_t)6 * HWSZ * 32 * 4;
    const int use_t = (ws_size >= need_tex) ? 1 : 0;

    PackArgs pa;
    pa.src[0] = pw1; pa.off[0] = WP_PW1; pa.din[0] = 59;  pa.dout[0] = 64;
    pa.src[1] = pw2; pa.off[1] = WP_PW2; pa.din[1] = 64;  pa.dout[1] = 32;
    pa.src[2] = fw1; pa.off[2] = WP_FW1; pa.din[2] = 64;  pa.dout[2] = 128;
    pa.src[3] = fw2; pa.off[3] = WP_FW2; pa.din[3] = 128; pa.dout[3] = 128;
    pa.src[4] = fw3; pa.off[4] = WP_FW3; pa.din[4] = 128; pa.dout[4] = 128;
    pa.src[5] = dw;  pa.off[5] = WP_DW;  pa.din[5] = 128; pa.dout[5] = 1;
    pa.src[6] = rw1; pa.off[6] = WP_RW1; pa.din[6] = 155; pa.dout[6] = 64;
    pa.src[7] = rw2; pa.off[7] = WP_RW2; pa.din[7] = 64;  pa.dout[7] = 32;

    k_pack<<<dim3(32, 8), 256, 0, stream>>>(pa, wswp);
    k_pts4<<<(NB*PP + 255)/256, 256, 0, stream>>>(pts, wspts4);
    if (use_t) k_transpose<<<6 * 256, 256, 0, stream>>>(tex, wstex);
    k_knn<<<NQ / 64, 1024, 0, stream>>>(coords, wspts4, pts, out + OUT_DIST_OFF, wsidx);
    k_sums<<<8, 1024, 0, stream>>>(out + OUT_DIST_OFF, wssums);
    k_main<<<NQ / 64, 1024, 0, stream>>>(coords, dirs, pts, tex, wstex, emb,
                                         wswp, pb1, pb2, fb1, fb2, fb3, db, rb1, rb2,
                                         wsidx, out + OUT_DIST_OFF, wssums, out, use_t);
}